// Round 2
// baseline (298.638 us; speedup 1.0000x reference)
//
#include <hip/hip_runtime.h>
#include <cstddef>
#include <cstdint>

#define LEAKY(s) ((s) >= 0.f ? (s) : 0.1f * (s))

constexpr int PTS    = 4096;   // H*W
constexpr int NBATCH = 32;
constexpr int NM     = 8;      // regions
constexpr int TILE   = 64;     // points per block in kA
constexpr int NTILES = PTS / TILE;  // 64

// ---------------- workspace layout (bytes) ----------------
// xs   : (B,128,8) f32                     @ 0        (131072)
// idx  : (B,128,8) i32                     @ 131072   (131072)  -- h1 (64KB) aliases after kD
// y4   : (B,4,1024) f32 partial conv_sp    @ 262144   (524288)
// part : (B,NTILES,1024) f32               @ 786432   (8 MB)    -- consumed by kB
// Dm   : (B,128,8,128) f32                 @ 786432   (16 MB)   -- aliases part (written after kB)
constexpr size_t OFF_XS   = 0;
constexpr size_t OFF_IDX  = 131072;
constexpr size_t OFF_Y4   = 262144;
constexpr size_t OFF_PART = 786432;
constexpr size_t OFF_DM   = 786432;

// ============================================================
// Kernel A: fused conv1(5->128) -> conv2 -> conv3 -> region-masked max partials
// grid (NTILES, B), 256 threads, 4 blocks/CU. LDS: act[128][64] + region[8][64]
// Thread (cg,pg): 8 channels (c0=cg*8) x 4 contiguous points (pl=pg*4).
// LDS rows are 64 floats = 256B; 16 lanes read contiguous float4s -> conflict-free.
// ============================================================
__device__ __forceinline__ void gemm64(const float* __restrict__ W,
                                       const float* act, int c0, int pl,
                                       float acc[8][4]) {
#pragma unroll
  for (int i = 0; i < 8; i++)
#pragma unroll
    for (int j = 0; j < 4; j++) acc[i][j] = 0.f;
  for (int k = 0; k < 128; k += 4) {
    float4 wv[8];
#pragma unroll
    for (int i = 0; i < 8; i++) wv[i] = *(const float4*)(W + (c0 + i) * 128 + k);
    float4 bl[4];
#pragma unroll
    for (int kk = 0; kk < 4; kk++) bl[kk] = *(const float4*)(act + (k + kk) * TILE + pl);
#pragma unroll
    for (int kk = 0; kk < 4; kk++) {
      float bv[4] = {bl[kk].x, bl[kk].y, bl[kk].z, bl[kk].w};
#pragma unroll
      for (int i = 0; i < 8; i++) {
        float w = (kk == 0) ? wv[i].x : (kk == 1) ? wv[i].y : (kk == 2) ? wv[i].z : wv[i].w;
#pragma unroll
        for (int j = 0; j < 4; j++) acc[i][j] = fmaf(w, bv[j], acc[i][j]);
      }
    }
  }
}

__global__ __launch_bounds__(256, 4) void kA(
    const float* __restrict__ coor, const float* __restrict__ region,
    const float* __restrict__ extents,
    const float* __restrict__ w1, const float* __restrict__ b1,
    const float* __restrict__ w2, const float* __restrict__ b2,
    const float* __restrict__ w3, const float* __restrict__ b3,
    float* __restrict__ part) {
  __shared__ float act[128 * TILE];
  __shared__ float reg_s[NM * TILE];
  const int tid = threadIdx.x;
  const int b = blockIdx.y;
  const int t0 = blockIdx.x * TILE;
  const int cg = tid >> 4, pg = tid & 15;
  const int c0 = cg * 8, pl = pg * 4;

  {  // stage region tile: 8 rows x 64 (2 floats/thread)
    int m = tid >> 5, j = tid & 31;
    float2 v = *(const float2*)(region + ((size_t)b * NM + m) * PTS + t0 + j * 2);
    *(float2*)(reg_s + m * TILE + j * 2) = v;
  }
  {  // layer 1 (K=5) directly from global
    float e0 = extents[b * 3], e1 = extents[b * 3 + 1], e2 = extents[b * 3 + 2];
    float in[5][4];
#pragma unroll
    for (int i = 0; i < 5; i++) {
      float4 a = *(const float4*)(coor + ((size_t)b * 5 + i) * PTS + t0 + pl);
      in[i][0] = a.x; in[i][1] = a.y; in[i][2] = a.z; in[i][3] = a.w;
    }
#pragma unroll
    for (int j = 0; j < 4; j++) {
      in[0][j] = (in[0][j] - 0.5f) * e0;
      in[1][j] = (in[1][j] - 0.5f) * e1;
      in[2][j] = (in[2][j] - 0.5f) * e2;
    }
#pragma unroll
    for (int i = 0; i < 8; i++) {
      int c = c0 + i;
      float wA = w1[c * 5], wB = w1[c * 5 + 1], wC = w1[c * 5 + 2],
            wD = w1[c * 5 + 3], wE = w1[c * 5 + 4];
      float bb = b1[c];
      float o[4];
#pragma unroll
      for (int j = 0; j < 4; j++) {
        float s = bb;
        s = fmaf(wA, in[0][j], s); s = fmaf(wB, in[1][j], s); s = fmaf(wC, in[2][j], s);
        s = fmaf(wD, in[3][j], s); s = fmaf(wE, in[4][j], s);
        o[j] = LEAKY(s);
      }
      float4 v = {o[0], o[1], o[2], o[3]};
      *(float4*)(act + c * TILE + pl) = v;
    }
  }
  __syncthreads();

  float acc[8][4];
  // layer 2
  gemm64(w2, act, c0, pl, acc);
  __syncthreads();  // everyone done reading act1
#pragma unroll
  for (int i = 0; i < 8; i++) {
    float bb = b2[c0 + i];
    float o[4];
#pragma unroll
    for (int j = 0; j < 4; j++) { float s = acc[i][j] + bb; o[j] = LEAKY(s); }
    float4 v = {o[0], o[1], o[2], o[3]};
    *(float4*)(act + (c0 + i) * TILE + pl) = v;
  }
  __syncthreads();
  // layer 3 (no activation)
  gemm64(w3, act, c0, pl, acc);
#pragma unroll
  for (int i = 0; i < 8; i++) {
    float bb = b3[c0 + i];
#pragma unroll
    for (int j = 0; j < 4; j++) acc[i][j] += bb;
  }
  __syncthreads();  // all act reads complete; reuse act[0..1023] as store funnel

  // region-masked max over this thread's 4 points, then in-wave reduce over 16 pgroups
#pragma unroll
  for (int m = 0; m < NM; m++) {
#pragma unroll
    for (int i = 0; i < 8; i++) {
      float mx = acc[i][0] * reg_s[m * TILE + pl];
#pragma unroll
      for (int j = 1; j < 4; j++) mx = fmaxf(mx, acc[i][j] * reg_s[m * TILE + pl + j]);
      mx = fmaxf(mx, __shfl_xor(mx, 1));
      mx = fmaxf(mx, __shfl_xor(mx, 2));
      mx = fmaxf(mx, __shfl_xor(mx, 4));
      mx = fmaxf(mx, __shfl_xor(mx, 8));
      if (pg == 0) act[(c0 + i) * 8 + m] = mx;
    }
  }
  __syncthreads();
  {  // coalesced store: part[b][tile][c*8+m]
    float4 v = *(const float4*)(act + tid * 4);
    *(float4*)(part + ((size_t)b * NTILES + blockIdx.x) * 1024 + tid * 4) = v;
  }
}

// ============================================================
// Kernel B: reduce partials -> pooled (128,8); softmax over channels per m;
// per-(b,c) descending sort of 8 region values -> idx. grid (B), 256 thr.
// part layout: (b, tile, c*8+m) -> coalesced stride-1024 reads.
// ============================================================
__global__ __launch_bounds__(256) void kB(const float* __restrict__ part,
                                          float* __restrict__ xs,
                                          int* __restrict__ idx) {
  __shared__ float pool[1024];
  __shared__ float xsl[1024];
  int b = blockIdx.x, tid = threadIdx.x;
#pragma unroll
  for (int q = 0; q < 4; q++) {
    int pair = tid + q * 256;
    const float* p = part + (size_t)b * (NTILES * 1024) + pair;
    float mx = p[0];
    for (int t = 1; t < NTILES; t++) mx = fmaxf(mx, p[(size_t)t * 1024]);
    pool[pair] = mx;
  }
  __syncthreads();
  // softmax over the 128 channels, one 32-lane group per m
  int m = tid >> 5, lane = tid & 31;
  float v[4];
#pragma unroll
  for (int j = 0; j < 4; j++) v[j] = pool[(lane + 32 * j) * 8 + m];
  float mx = fmaxf(fmaxf(v[0], v[1]), fmaxf(v[2], v[3]));
#pragma unroll
  for (int d = 1; d < 32; d <<= 1) mx = fmaxf(mx, __shfl_xor(mx, d, 32));
  float e[4]; float s = 0.f;
#pragma unroll
  for (int j = 0; j < 4; j++) { e[j] = expf(v[j] - mx); s += e[j]; }
#pragma unroll
  for (int d = 1; d < 32; d <<= 1) s += __shfl_xor(s, d, 32);
#pragma unroll
  for (int j = 0; j < 4; j++) {
    float x = e[j] / s;
    int c = lane + 32 * j;
    xsl[c * 8 + m] = x;
    xs[(size_t)b * 1024 + c * 8 + m] = x;
  }
  __syncthreads();
  if (tid < 128) {
    float vv[8];
#pragma unroll
    for (int n = 0; n < 8; n++) vv[n] = xsl[tid * 8 + n];
    int used = 0;
#pragma unroll
    for (int n = 0; n < 8; n++) {
      int best = 0; float bvv = -1.f;
#pragma unroll
      for (int q = 0; q < 8; q++) {
        bool ok = ((used >> q) & 1) == 0;
        if (ok && vv[q] > bvv) { bvv = vv[q]; best = q; }  // strict > == lowest-index tie-break
      }
      used |= 1 << best;
      idx[(size_t)b * 1024 + tid * 8 + n] = best;
    }
  }
}

// ============================================================
// Kernel C: D[b,k,m,o] = sum_c xs[b,c,m] * w_sp[o,c,k]
// grid (32 ktiles of 4, 8 bgroups of 4), 256 thr.
// ============================================================
__global__ __launch_bounds__(256) void kC(const float* __restrict__ xs,
                                          const float* __restrict__ w_sp,
                                          float* __restrict__ Dm) {
  __shared__ float As[16 * 512];
  __shared__ float Bs[16 * 32];
  const int tid = threadIdx.x;
  const int k0 = blockIdx.x * 4;
  const int bbase = blockIdx.y * 4;
  const int rg = tid & 63, cgq = tid >> 6;
  const int j0 = cgq * 8;
  float acc[8][8];
#pragma unroll
  for (int i = 0; i < 8; i++)
#pragma unroll
    for (int j = 0; j < 8; j++) acc[i][j] = 0.f;

  for (int c0 = 0; c0 < 128; c0 += 16) {
    __syncthreads();
#pragma unroll
    for (int it = 0; it < 8; it++) {
      int q = tid + it * 256;             // 0..2047
      int o = q >> 4, cc = q & 15;
      float4 w = *(const float4*)(w_sp + (size_t)o * 16384 + (size_t)(c0 + cc) * 128 + k0);
      As[cc * 512 + o]       = w.x;
      As[cc * 512 + 128 + o] = w.y;
      As[cc * 512 + 256 + o] = w.z;
      As[cc * 512 + 384 + o] = w.w;
    }
#pragma unroll
    for (int it = 0; it < 2; it++) {
      int f = tid + it * 256;             // 0..511 = bl*128 + cc*8 + m
      int bl = f >> 7, rem = f & 127;
      Bs[(rem >> 3) * 32 + bl * 8 + (rem & 7)] =
          xs[((size_t)(bbase + bl) * 128 + c0 + (rem >> 3)) * 8 + (rem & 7)];
    }
    __syncthreads();
#pragma unroll
    for (int cc = 0; cc < 16; cc++) {
      float4 a0 = *(const float4*)(As + cc * 512 + rg * 4);
      float4 a1 = *(const float4*)(As + cc * 512 + 256 + rg * 4);
      float4 p0 = *(const float4*)(Bs + cc * 32 + j0);
      float4 p1 = *(const float4*)(Bs + cc * 32 + j0 + 4);
      float av[8] = {a0.x, a0.y, a0.z, a0.w, a1.x, a1.y, a1.z, a1.w};
      float bv[8] = {p0.x, p0.y, p0.z, p0.w, p1.x, p1.y, p1.z, p1.w};
#pragma unroll
      for (int i = 0; i < 8; i++)
#pragma unroll
        for (int j = 0; j < 8; j++) acc[i][j] = fmaf(av[i], bv[j], acc[i][j]);
    }
  }
#pragma unroll
  for (int j = 0; j < 8; j++) {
    int col = j0 + j;
    int bl = col >> 3, m = col & 7, bb = bbase + bl;
    {
      int r = rg * 4;
      int kk = r >> 7, o = r & 127;
      float4 v = {acc[0][j], acc[1][j], acc[2][j], acc[3][j]};
      *(float4*)(Dm + (((size_t)bb * 128 + k0 + kk) * 8 + m) * 128 + o) = v;
    }
    {
      int r = 256 + rg * 4;
      int kk = r >> 7, o = r & 127;
      float4 v = {acc[4][j], acc[5][j], acc[6][j], acc[7][j]};
      *(float4*)(Dm + (((size_t)bb * 128 + k0 + kk) * 8 + m) * 128 + o) = v;
    }
  }
}

// ============================================================
// Kernel D: partial gather-sum y4[b,kq,o*8+r] = sum_{k in kq} D[b,k,idx[b,k,r],o]
// grid (B, 4), 256 thr.
// ============================================================
__global__ __launch_bounds__(256) void kD(const float* __restrict__ Dm,
                                          const int* __restrict__ idx,
                                          float* __restrict__ y4) {
  __shared__ int il[256];  // 32 k x 8 r
  int b = blockIdx.x, kq = blockIdx.y;
  int tid = threadIdx.x;
  il[tid] = idx[(size_t)b * 1024 + kq * 256 + tid];
  __syncthreads();
  int o = tid & 127, half = tid >> 7;
  const float* Db = Dm + (size_t)b * 131072 + (size_t)kq * 32 * 1024;
  float s0 = 0, s1 = 0, s2 = 0, s3 = 0;
  for (int k = 0; k < 32; k++) {
    const float* Dk = Db + k * 1024;
    const int* ik = il + k * 8 + half * 4;
    s0 += Dk[ik[0] * 128 + o];
    s1 += Dk[ik[1] * 128 + o];
    s2 += Dk[ik[2] * 128 + o];
    s3 += Dk[ik[3] * 128 + o];
  }
  float* yo = y4 + ((size_t)b * 4 + kq) * 1024 + o * 8 + half * 4;
  yo[0] = s0; yo[1] = s1; yo[2] = s2; yo[3] = s3;
}

// ============================================================
// Kernel E1: assemble y (sum kq partials + b_sp + leaky), fc1 -> h1.
// grid (B, 8), 256 thr; wave-per-output, coalesced 4KB weight rows.
// ============================================================
__global__ __launch_bounds__(256) void kE1(
    const float* __restrict__ y4, const float* __restrict__ b_sp,
    const float* __restrict__ fc1_w, const float* __restrict__ fc1_b,
    float* __restrict__ h1) {
  __shared__ float yl[1024];
  int b = blockIdx.x, og = blockIdx.y, tid = threadIdx.x;
  {
    int f0 = tid * 4;
    const float* base = y4 + (size_t)b * 4096;
    float4 a0 = *(const float4*)(base + f0);
    float4 a1 = *(const float4*)(base + 1024 + f0);
    float4 a2 = *(const float4*)(base + 2048 + f0);
    float4 a3 = *(const float4*)(base + 3072 + f0);
    float v[4] = {a0.x + a1.x + a2.x + a3.x, a0.y + a1.y + a2.y + a3.y,
                  a0.z + a1.z + a2.z + a3.z, a0.w + a1.w + a2.w + a3.w};
    float o[4];
#pragma unroll
    for (int j = 0; j < 4; j++) {
      int f = f0 + j;
      float s = v[j] + b_sp[f >> 3];
      o[j] = LEAKY(s);
    }
    float4 vv = {o[0], o[1], o[2], o[3]};
    *(float4*)(yl + f0) = vv;
  }
  __syncthreads();
  int wid = tid >> 6, lane = tid & 63;
  const float4* ylv = (const float4*)yl;
#pragma unroll
  for (int pass = 0; pass < 16; pass++) {
    int o = og * 64 + pass * 4 + wid;
    const float4* wr = (const float4*)(fc1_w + (size_t)o * 1024);
    float sa = 0, sb = 0, sc = 0, sd = 0;
#pragma unroll
    for (int r = 0; r < 4; r++) {
      float4 w = wr[r * 64 + lane];
      float4 u = ylv[r * 64 + lane];
      sa = fmaf(w.x, u.x, sa); sb = fmaf(w.y, u.y, sb);
      sc = fmaf(w.z, u.z, sc); sd = fmaf(w.w, u.w, sd);
    }
    float s = (sa + sb) + (sc + sd);
#pragma unroll
    for (int d = 1; d < 64; d <<= 1) s += __shfl_xor(s, d);
    if (lane == 0) {
      float t = s + fc1_b[o];
      h1[(size_t)b * 512 + o] = LEAKY(t);
    }
  }
}

// ============================================================
// Kernel E2: fc2 -> heads. grid (B), 256 thr (thread-per-output fc2).
// ============================================================
__global__ __launch_bounds__(256) void kE2(
    const float* __restrict__ h1, const float* __restrict__ fc2_w,
    const float* __restrict__ fc2_b,
    const float* __restrict__ fcr_w, const float* __restrict__ fcr_b,
    const float* __restrict__ fct_w, const float* __restrict__ fct_b,
    float* __restrict__ out) {
  __shared__ float h1l[512];
  __shared__ float h2[256];
  int b = blockIdx.x, tid = threadIdx.x;
  if (tid < 128) {
    float4 v = *(const float4*)(h1 + (size_t)b * 512 + tid * 4);
    *(float4*)(h1l + tid * 4) = v;
  }
  __syncthreads();
  {
    int o = tid;
    const float4* wr = (const float4*)(fc2_w + (size_t)o * 512);
    const float4* uv = (const float4*)h1l;
    float sa = 0, sb = 0, sc = 0, sd = 0;
#pragma unroll 4
    for (int q = 0; q < 128; q++) {
      float4 w = wr[q];
      float4 u = uv[q];
      sa = fmaf(w.x, u.x, sa); sb = fmaf(w.y, u.y, sb);
      sc = fmaf(w.z, u.z, sc); sd = fmaf(w.w, u.w, sd);
    }
    float s = (sa + sb) + (sc + sd) + fc2_b[o];
    h2[o] = LEAKY(s);
  }
  __syncthreads();
  if (tid < 7) {
    bool isrot = tid < 4;
    int o = isrot ? tid : tid - 4;
    const float4* wr = (const float4*)((isrot ? fcr_w : fct_w) + (size_t)o * 256);
    const float4* uv = (const float4*)h2;
    float sa = 0, sb = 0, sc = 0, sd = 0;
#pragma unroll 4
    for (int q = 0; q < 64; q++) {
      float4 w = wr[q];
      float4 u = uv[q];
      sa = fmaf(w.x, u.x, sa); sb = fmaf(w.y, u.y, sb);
      sc = fmaf(w.z, u.z, sc); sd = fmaf(w.w, u.w, sd);
    }
    float s = (sa + sb) + (sc + sd) + (isrot ? fcr_b[o] : fct_b[o]);
    out[isrot ? (b * 4 + o) : (128 + b * 3 + o)] = s;
  }
}

extern "C" void kernel_launch(void* const* d_in, const int* in_sizes, int n_in,
                              void* d_out, int out_size, void* d_ws, size_t ws_size,
                              hipStream_t stream) {
  const float* coor    = (const float*)d_in[0];
  const float* region  = (const float*)d_in[1];
  const float* extents = (const float*)d_in[2];
  const float* w1 = (const float*)d_in[3];  const float* b1 = (const float*)d_in[4];
  const float* w2 = (const float*)d_in[5];  const float* b2 = (const float*)d_in[6];
  const float* w3 = (const float*)d_in[7];  const float* b3 = (const float*)d_in[8];
  const float* w_sp = (const float*)d_in[9];  const float* b_sp = (const float*)d_in[10];
  const float* fc1_w = (const float*)d_in[11]; const float* fc1_b = (const float*)d_in[12];
  const float* fc2_w = (const float*)d_in[13]; const float* fc2_b = (const float*)d_in[14];
  const float* fcr_w = (const float*)d_in[15]; const float* fcr_b = (const float*)d_in[16];
  const float* fct_w = (const float*)d_in[17]; const float* fct_b = (const float*)d_in[18];

  char* ws = (char*)d_ws;
  float* xs   = (float*)(ws + OFF_XS);
  int*   idx  = (int*)(ws + OFF_IDX);
  float* y4   = (float*)(ws + OFF_Y4);
  float* part = (float*)(ws + OFF_PART);
  float* Dm   = (float*)(ws + OFF_DM);   // aliases part: written only after kB consumed part
  float* h1   = (float*)(ws + OFF_IDX);  // aliases idx: written only after kD consumed idx
  float* out  = (float*)d_out;

  kA<<<dim3(NTILES, NBATCH), 256, 0, stream>>>(coor, region, extents,
                                               w1, b1, w2, b2, w3, b3, part);
  kB<<<dim3(NBATCH), 256, 0, stream>>>(part, xs, idx);
  kC<<<dim3(32, 8), 256, 0, stream>>>(xs, w_sp, Dm);
  kD<<<dim3(NBATCH, 4), 256, 0, stream>>>(Dm, idx, y4);
  kE1<<<dim3(NBATCH, 8), 256, 0, stream>>>(y4, b_sp, fc1_w, fc1_b, h1);
  kE2<<<dim3(NBATCH), 256, 0, stream>>>(h1, fc2_w, fc2_b, fcr_w, fcr_b,
                                        fct_w, fct_b, out);
}

// Round 3
// 270.044 us; speedup vs baseline: 1.1059x; 1.1059x over previous
//
#include <hip/hip_runtime.h>
#include <cstddef>
#include <cstdint>

#define LEAKY(s) ((s) >= 0.f ? (s) : 0.1f * (s))

constexpr int PTS    = 4096;   // H*W
constexpr int NBATCH = 32;
constexpr int NM     = 8;      // regions
constexpr int TILE   = 128;    // points per block in kA
constexpr int NTILES = PTS / TILE;  // 32

// ---------------- workspace layout (bytes) ----------------
// xs   : (B,128,8) f32                     @ 0        (131072)
// idx  : (B,128,8) i32                     @ 131072   (131072)  -- h1 (64KB) aliases after kD
// y4   : (B,4,1024) f32 partial conv_sp    @ 262144   (524288)
// part : (B,NTILES,1024) f32               @ 786432   (4 MB)    -- consumed by kB
// Dm   : (B,128,8,128) f32                 @ 786432   (16 MB)   -- aliases part (written after kB)
constexpr size_t OFF_XS   = 0;
constexpr size_t OFF_IDX  = 131072;
constexpr size_t OFF_Y4   = 262144;
constexpr size_t OFF_PART = 786432;
constexpr size_t OFF_DM   = 786432;

// ============================================================
// Kernel A: fused conv1(5->128) -> conv2 -> conv3 -> region-masked max partials
// grid (NTILES, B), 256 threads, 2 blocks/CU (69.6KB LDS).
// Thread (cg,pg): 8 channels (c0=cg*8) x 8 points split as pl0=pg*4, pl1=64+pg*4.
// LDS rows 128 floats = 512B; 16 lanes read contiguous 256B float4 chunks
// (2-way = free); cg groups broadcast same address. K-loop explicitly
// software-pipelined (2-chunk ping-pong) to cover L2/LDS latency at low TLP.
// ============================================================
struct Chunk {
  float4 wv[8];
  float4 b0[4];
  float4 b1[4];
};

__device__ __forceinline__ void loadChunk(Chunk& ch, const float* __restrict__ W,
                                          const float* act, int c0, int pl0, int pl1,
                                          int k) {
#pragma unroll
  for (int i = 0; i < 8; i++) ch.wv[i] = *(const float4*)(W + (c0 + i) * 128 + k);
#pragma unroll
  for (int kk = 0; kk < 4; kk++) {
    ch.b0[kk] = *(const float4*)(act + (k + kk) * TILE + pl0);
    ch.b1[kk] = *(const float4*)(act + (k + kk) * TILE + pl1);
  }
}

__device__ __forceinline__ void macChunk(const Chunk& ch, float acc[8][8]) {
#pragma unroll
  for (int kk = 0; kk < 4; kk++) {
    float bv[8] = {kk == 0 ? ch.b0[0].x : kk == 1 ? ch.b0[1].x : kk == 2 ? ch.b0[2].x : ch.b0[3].x,
                   0, 0, 0, 0, 0, 0, 0};
    // unpack cleanly (static indices only)
    float4 q0 = ch.b0[kk], q1 = ch.b1[kk];
    bv[0] = q0.x; bv[1] = q0.y; bv[2] = q0.z; bv[3] = q0.w;
    bv[4] = q1.x; bv[5] = q1.y; bv[6] = q1.z; bv[7] = q1.w;
#pragma unroll
    for (int i = 0; i < 8; i++) {
      float w = (kk == 0) ? ch.wv[i].x : (kk == 1) ? ch.wv[i].y : (kk == 2) ? ch.wv[i].z : ch.wv[i].w;
#pragma unroll
      for (int j = 0; j < 8; j++) acc[i][j] = fmaf(w, bv[j], acc[i][j]);
    }
  }
}

__device__ __forceinline__ void gemm128p(const float* __restrict__ W,
                                         const float* act, int c0, int pl0, int pl1,
                                         float acc[8][8]) {
#pragma unroll
  for (int i = 0; i < 8; i++)
#pragma unroll
    for (int j = 0; j < 8; j++) acc[i][j] = 0.f;
  Chunk A, B;
  loadChunk(A, W, act, c0, pl0, pl1, 0);
  for (int k = 0; k < 128; k += 8) {
    loadChunk(B, W, act, c0, pl0, pl1, k + 4);
    macChunk(A, acc);
    if (k + 8 < 128) loadChunk(A, W, act, c0, pl0, pl1, k + 8);
    macChunk(B, acc);
  }
}

__global__ __launch_bounds__(256, 1) void kA(
    const float* __restrict__ coor, const float* __restrict__ region,
    const float* __restrict__ extents,
    const float* __restrict__ w1, const float* __restrict__ b1,
    const float* __restrict__ w2, const float* __restrict__ b2,
    const float* __restrict__ w3, const float* __restrict__ b3,
    float* __restrict__ part) {
  __shared__ float act[128 * TILE];
  __shared__ float reg_s[NM * TILE];
  const int tid = threadIdx.x;
  const int b = blockIdx.y;
  const int t0 = blockIdx.x * TILE;
  const int cg = tid >> 4, pg = tid & 15;
  const int c0 = cg * 8, pl0 = pg * 4, pl1 = 64 + pg * 4;

  {  // stage region tile: 8 rows x 128 (float4/thread)
    int m = tid >> 5, j = tid & 31;
    float4 v = *(const float4*)(region + ((size_t)b * NM + m) * PTS + t0 + j * 4);
    *(float4*)(reg_s + m * TILE + j * 4) = v;
  }
  {  // layer 1 (K=5) directly from global
    float e0 = extents[b * 3], e1 = extents[b * 3 + 1], e2 = extents[b * 3 + 2];
    float in[5][8];
#pragma unroll
    for (int i = 0; i < 5; i++) {
      float4 a = *(const float4*)(coor + ((size_t)b * 5 + i) * PTS + t0 + pl0);
      float4 c4 = *(const float4*)(coor + ((size_t)b * 5 + i) * PTS + t0 + pl1);
      in[i][0] = a.x;  in[i][1] = a.y;  in[i][2] = a.z;  in[i][3] = a.w;
      in[i][4] = c4.x; in[i][5] = c4.y; in[i][6] = c4.z; in[i][7] = c4.w;
    }
#pragma unroll
    for (int j = 0; j < 8; j++) {
      in[0][j] = (in[0][j] - 0.5f) * e0;
      in[1][j] = (in[1][j] - 0.5f) * e1;
      in[2][j] = (in[2][j] - 0.5f) * e2;
    }
#pragma unroll
    for (int i = 0; i < 8; i++) {
      int c = c0 + i;
      float wA = w1[c * 5], wB = w1[c * 5 + 1], wC = w1[c * 5 + 2],
            wD = w1[c * 5 + 3], wE = w1[c * 5 + 4];
      float bb = b1[c];
      float o[8];
#pragma unroll
      for (int j = 0; j < 8; j++) {
        float s = bb;
        s = fmaf(wA, in[0][j], s); s = fmaf(wB, in[1][j], s); s = fmaf(wC, in[2][j], s);
        s = fmaf(wD, in[3][j], s); s = fmaf(wE, in[4][j], s);
        o[j] = LEAKY(s);
      }
      float4 v0 = {o[0], o[1], o[2], o[3]}, v1 = {o[4], o[5], o[6], o[7]};
      *(float4*)(act + c * TILE + pl0) = v0;
      *(float4*)(act + c * TILE + pl1) = v1;
    }
  }
  __syncthreads();

  float acc[8][8];
  // layer 2
  gemm128p(w2, act, c0, pl0, pl1, acc);
  __syncthreads();  // everyone done reading act1
#pragma unroll
  for (int i = 0; i < 8; i++) {
    float bb = b2[c0 + i];
    float o[8];
#pragma unroll
    for (int j = 0; j < 8; j++) { float s = acc[i][j] + bb; o[j] = LEAKY(s); }
    float4 v0 = {o[0], o[1], o[2], o[3]}, v1 = {o[4], o[5], o[6], o[7]};
    *(float4*)(act + (c0 + i) * TILE + pl0) = v0;
    *(float4*)(act + (c0 + i) * TILE + pl1) = v1;
  }
  __syncthreads();
  // layer 3 (no activation)
  gemm128p(w3, act, c0, pl0, pl1, acc);
#pragma unroll
  for (int i = 0; i < 8; i++) {
    float bb = b3[c0 + i];
#pragma unroll
    for (int j = 0; j < 8; j++) acc[i][j] += bb;
  }
  __syncthreads();  // all act reads complete; reuse act[0..1023] as store funnel

  // region-masked max over this thread's 8 points, then in-wave reduce over 16 pgroups
#pragma unroll
  for (int m = 0; m < NM; m++) {
    float4 r0 = *(const float4*)(reg_s + m * TILE + pl0);
    float4 r1 = *(const float4*)(reg_s + m * TILE + pl1);
    float rv[8] = {r0.x, r0.y, r0.z, r0.w, r1.x, r1.y, r1.z, r1.w};
#pragma unroll
    for (int i = 0; i < 8; i++) {
      float mx = acc[i][0] * rv[0];
#pragma unroll
      for (int j = 1; j < 8; j++) mx = fmaxf(mx, acc[i][j] * rv[j]);
      mx = fmaxf(mx, __shfl_xor(mx, 1));
      mx = fmaxf(mx, __shfl_xor(mx, 2));
      mx = fmaxf(mx, __shfl_xor(mx, 4));
      mx = fmaxf(mx, __shfl_xor(mx, 8));
      if (pg == 0) act[(c0 + i) * 8 + m] = mx;
    }
  }
  __syncthreads();
  {  // coalesced store: part[b][tile][c*8+m]
    float4 v = *(const float4*)(act + tid * 4);
    *(float4*)(part + ((size_t)b * NTILES + blockIdx.x) * 1024 + tid * 4) = v;
  }
}

// ============================================================
// Kernel B: reduce partials -> pooled (128,8); softmax over channels per m;
// per-(b,c) descending sort of 8 region values -> idx. grid (B), 256 thr.
// part layout: (b, tile, c*8+m) -> stride-1024 reads, coalesced across threads.
// ============================================================
__global__ __launch_bounds__(256) void kB(const float* __restrict__ part,
                                          float* __restrict__ xs,
                                          int* __restrict__ idx) {
  __shared__ float pool[1024];
  __shared__ float xsl[1024];
  int b = blockIdx.x, tid = threadIdx.x;
#pragma unroll
  for (int q = 0; q < 4; q++) {
    int pair = tid + q * 256;
    const float* p = part + (size_t)b * (NTILES * 1024) + pair;
    float mx = p[0];
    for (int t = 1; t < NTILES; t++) mx = fmaxf(mx, p[(size_t)t * 1024]);
    pool[pair] = mx;
  }
  __syncthreads();
  // softmax over the 128 channels, one 32-lane group per m
  int m = tid >> 5, lane = tid & 31;
  float v[4];
#pragma unroll
  for (int j = 0; j < 4; j++) v[j] = pool[(lane + 32 * j) * 8 + m];
  float mx = fmaxf(fmaxf(v[0], v[1]), fmaxf(v[2], v[3]));
#pragma unroll
  for (int d = 1; d < 32; d <<= 1) mx = fmaxf(mx, __shfl_xor(mx, d, 32));
  float e[4]; float s = 0.f;
#pragma unroll
  for (int j = 0; j < 4; j++) { e[j] = expf(v[j] - mx); s += e[j]; }
#pragma unroll
  for (int d = 1; d < 32; d <<= 1) s += __shfl_xor(s, d, 32);
#pragma unroll
  for (int j = 0; j < 4; j++) {
    float x = e[j] / s;
    int c = lane + 32 * j;
    xsl[c * 8 + m] = x;
    xs[(size_t)b * 1024 + c * 8 + m] = x;
  }
  __syncthreads();
  if (tid < 128) {
    float vv[8];
#pragma unroll
    for (int n = 0; n < 8; n++) vv[n] = xsl[tid * 8 + n];
    int used = 0;
#pragma unroll
    for (int n = 0; n < 8; n++) {
      int best = 0; float bvv = -1.f;
#pragma unroll
      for (int q = 0; q < 8; q++) {
        bool ok = ((used >> q) & 1) == 0;
        if (ok && vv[q] > bvv) { bvv = vv[q]; best = q; }  // strict > == lowest-index tie-break
      }
      used |= 1 << best;
      idx[(size_t)b * 1024 + tid * 8 + n] = best;
    }
  }
}

// ============================================================
// Kernel C: D[b,k,m,o] = sum_c xs[b,c,m] * w_sp[o,c,k]
// grid (32 ktiles of 4, 8 bgroups of 4), 256 thr.
// ============================================================
__global__ __launch_bounds__(256) void kC(const float* __restrict__ xs,
                                          const float* __restrict__ w_sp,
                                          float* __restrict__ Dm) {
  __shared__ float As[16 * 512];
  __shared__ float Bs[16 * 32];
  const int tid = threadIdx.x;
  const int k0 = blockIdx.x * 4;
  const int bbase = blockIdx.y * 4;
  const int rg = tid & 63, cgq = tid >> 6;
  const int j0 = cgq * 8;
  float acc[8][8];
#pragma unroll
  for (int i = 0; i < 8; i++)
#pragma unroll
    for (int j = 0; j < 8; j++) acc[i][j] = 0.f;

  for (int c0 = 0; c0 < 128; c0 += 16) {
    __syncthreads();
#pragma unroll
    for (int it = 0; it < 8; it++) {
      int q = tid + it * 256;             // 0..2047
      int o = q >> 4, cc = q & 15;
      float4 w = *(const float4*)(w_sp + (size_t)o * 16384 + (size_t)(c0 + cc) * 128 + k0);
      As[cc * 512 + o]       = w.x;
      As[cc * 512 + 128 + o] = w.y;
      As[cc * 512 + 256 + o] = w.z;
      As[cc * 512 + 384 + o] = w.w;
    }
#pragma unroll
    for (int it = 0; it < 2; it++) {
      int f = tid + it * 256;             // 0..511 = bl*128 + cc*8 + m
      int bl = f >> 7, rem = f & 127;
      Bs[(rem >> 3) * 32 + bl * 8 + (rem & 7)] =
          xs[((size_t)(bbase + bl) * 128 + c0 + (rem >> 3)) * 8 + (rem & 7)];
    }
    __syncthreads();
#pragma unroll
    for (int cc = 0; cc < 16; cc++) {
      float4 a0 = *(const float4*)(As + cc * 512 + rg * 4);
      float4 a1 = *(const float4*)(As + cc * 512 + 256 + rg * 4);
      float4 p0 = *(const float4*)(Bs + cc * 32 + j0);
      float4 p1 = *(const float4*)(Bs + cc * 32 + j0 + 4);
      float av[8] = {a0.x, a0.y, a0.z, a0.w, a1.x, a1.y, a1.z, a1.w};
      float bv[8] = {p0.x, p0.y, p0.z, p0.w, p1.x, p1.y, p1.z, p1.w};
#pragma unroll
      for (int i = 0; i < 8; i++)
#pragma unroll
        for (int j = 0; j < 8; j++) acc[i][j] = fmaf(av[i], bv[j], acc[i][j]);
    }
  }
#pragma unroll
  for (int j = 0; j < 8; j++) {
    int col = j0 + j;
    int bl = col >> 3, m = col & 7, bb = bbase + bl;
    {
      int r = rg * 4;
      int kk = r >> 7, o = r & 127;
      float4 v = {acc[0][j], acc[1][j], acc[2][j], acc[3][j]};
      *(float4*)(Dm + (((size_t)bb * 128 + k0 + kk) * 8 + m) * 128 + o) = v;
    }
    {
      int r = 256 + rg * 4;
      int kk = r >> 7, o = r & 127;
      float4 v = {acc[4][j], acc[5][j], acc[6][j], acc[7][j]};
      *(float4*)(Dm + (((size_t)bb * 128 + k0 + kk) * 8 + m) * 128 + o) = v;
    }
  }
}

// ============================================================
// Kernel D: partial gather-sum y4[b,kq,o*8+r] = sum_{k in kq} D[b,k,idx[b,k,r],o]
// grid (B, 4), 256 thr.
// ============================================================
__global__ __launch_bounds__(256) void kD(const float* __restrict__ Dm,
                                          const int* __restrict__ idx,
                                          float* __restrict__ y4) {
  __shared__ int il[256];  // 32 k x 8 r
  int b = blockIdx.x, kq = blockIdx.y;
  int tid = threadIdx.x;
  il[tid] = idx[(size_t)b * 1024 + kq * 256 + tid];
  __syncthreads();
  int o = tid & 127, half = tid >> 7;
  const float* Db = Dm + (size_t)b * 131072 + (size_t)kq * 32 * 1024;
  float s0 = 0, s1 = 0, s2 = 0, s3 = 0;
  for (int k = 0; k < 32; k++) {
    const float* Dk = Db + k * 1024;
    const int* ik = il + k * 8 + half * 4;
    s0 += Dk[ik[0] * 128 + o];
    s1 += Dk[ik[1] * 128 + o];
    s2 += Dk[ik[2] * 128 + o];
    s3 += Dk[ik[3] * 128 + o];
  }
  float* yo = y4 + ((size_t)b * 4 + kq) * 1024 + o * 8 + half * 4;
  yo[0] = s0; yo[1] = s1; yo[2] = s2; yo[3] = s3;
}

// ============================================================
// Kernel E1: assemble y (sum kq partials + b_sp + leaky), fc1 -> h1.
// grid (B, 8), 256 thr; wave-per-output, coalesced 4KB weight rows.
// ============================================================
__global__ __launch_bounds__(256) void kE1(
    const float* __restrict__ y4, const float* __restrict__ b_sp,
    const float* __restrict__ fc1_w, const float* __restrict__ fc1_b,
    float* __restrict__ h1) {
  __shared__ float yl[1024];
  int b = blockIdx.x, og = blockIdx.y, tid = threadIdx.x;
  {
    int f0 = tid * 4;
    const float* base = y4 + (size_t)b * 4096;
    float4 a0 = *(const float4*)(base + f0);
    float4 a1 = *(const float4*)(base + 1024 + f0);
    float4 a2 = *(const float4*)(base + 2048 + f0);
    float4 a3 = *(const float4*)(base + 3072 + f0);
    float v[4] = {a0.x + a1.x + a2.x + a3.x, a0.y + a1.y + a2.y + a3.y,
                  a0.z + a1.z + a2.z + a3.z, a0.w + a1.w + a2.w + a3.w};
    float o[4];
#pragma unroll
    for (int j = 0; j < 4; j++) {
      int f = f0 + j;
      float s = v[j] + b_sp[f >> 3];
      o[j] = LEAKY(s);
    }
    float4 vv = {o[0], o[1], o[2], o[3]};
    *(float4*)(yl + f0) = vv;
  }
  __syncthreads();
  int wid = tid >> 6, lane = tid & 63;
  const float4* ylv = (const float4*)yl;
#pragma unroll
  for (int pass = 0; pass < 16; pass++) {
    int o = og * 64 + pass * 4 + wid;
    const float4* wr = (const float4*)(fc1_w + (size_t)o * 1024);
    float sa = 0, sb = 0, sc = 0, sd = 0;
#pragma unroll
    for (int r = 0; r < 4; r++) {
      float4 w = wr[r * 64 + lane];
      float4 u = ylv[r * 64 + lane];
      sa = fmaf(w.x, u.x, sa); sb = fmaf(w.y, u.y, sb);
      sc = fmaf(w.z, u.z, sc); sd = fmaf(w.w, u.w, sd);
    }
    float s = (sa + sb) + (sc + sd);
#pragma unroll
    for (int d = 1; d < 64; d <<= 1) s += __shfl_xor(s, d);
    if (lane == 0) {
      float t = s + fc1_b[o];
      h1[(size_t)b * 512 + o] = LEAKY(t);
    }
  }
}

// ============================================================
// Kernel E2: fc2 -> heads. grid (B), 256 thr (thread-per-output fc2).
// ============================================================
__global__ __launch_bounds__(256) void kE2(
    const float* __restrict__ h1, const float* __restrict__ fc2_w,
    const float* __restrict__ fc2_b,
    const float* __restrict__ fcr_w, const float* __restrict__ fcr_b,
    const float* __restrict__ fct_w, const float* __restrict__ fct_b,
    float* __restrict__ out) {
  __shared__ float h1l[512];
  __shared__ float h2[256];
  int b = blockIdx.x, tid = threadIdx.x;
  if (tid < 128) {
    float4 v = *(const float4*)(h1 + (size_t)b * 512 + tid * 4);
    *(float4*)(h1l + tid * 4) = v;
  }
  __syncthreads();
  {
    int o = tid;
    const float4* wr = (const float4*)(fc2_w + (size_t)o * 512);
    const float4* uv = (const float4*)h1l;
    float sa = 0, sb = 0, sc = 0, sd = 0;
#pragma unroll 4
    for (int q = 0; q < 128; q++) {
      float4 w = wr[q];
      float4 u = uv[q];
      sa = fmaf(w.x, u.x, sa); sb = fmaf(w.y, u.y, sb);
      sc = fmaf(w.z, u.z, sc); sd = fmaf(w.w, u.w, sd);
    }
    float s = (sa + sb) + (sc + sd) + fc2_b[o];
    h2[o] = LEAKY(s);
  }
  __syncthreads();
  if (tid < 7) {
    bool isrot = tid < 4;
    int o = isrot ? tid : tid - 4;
    const float4* wr = (const float4*)((isrot ? fcr_w : fct_w) + (size_t)o * 256);
    const float4* uv = (const float4*)h2;
    float sa = 0, sb = 0, sc = 0, sd = 0;
#pragma unroll 4
    for (int q = 0; q < 64; q++) {
      float4 w = wr[q];
      float4 u = uv[q];
      sa = fmaf(w.x, u.x, sa); sb = fmaf(w.y, u.y, sb);
      sc = fmaf(w.z, u.z, sc); sd = fmaf(w.w, u.w, sd);
    }
    float s = (sa + sb) + (sc + sd) + (isrot ? fcr_b[o] : fct_b[o]);
    out[isrot ? (b * 4 + o) : (128 + b * 3 + o)] = s;
  }
}

extern "C" void kernel_launch(void* const* d_in, const int* in_sizes, int n_in,
                              void* d_out, int out_size, void* d_ws, size_t ws_size,
                              hipStream_t stream) {
  const float* coor    = (const float*)d_in[0];
  const float* region  = (const float*)d_in[1];
  const float* extents = (const float*)d_in[2];
  const float* w1 = (const float*)d_in[3];  const float* b1 = (const float*)d_in[4];
  const float* w2 = (const float*)d_in[5];  const float* b2 = (const float*)d_in[6];
  const float* w3 = (const float*)d_in[7];  const float* b3 = (const float*)d_in[8];
  const float* w_sp = (const float*)d_in[9];  const float* b_sp = (const float*)d_in[10];
  const float* fc1_w = (const float*)d_in[11]; const float* fc1_b = (const float*)d_in[12];
  const float* fc2_w = (const float*)d_in[13]; const float* fc2_b = (const float*)d_in[14];
  const float* fcr_w = (const float*)d_in[15]; const float* fcr_b = (const float*)d_in[16];
  const float* fct_w = (const float*)d_in[17]; const float* fct_b = (const float*)d_in[18];

  char* ws = (char*)d_ws;
  float* xs   = (float*)(ws + OFF_XS);
  int*   idx  = (int*)(ws + OFF_IDX);
  float* y4   = (float*)(ws + OFF_Y4);
  float* part = (float*)(ws + OFF_PART);
  float* Dm   = (float*)(ws + OFF_DM);   // aliases part: written only after kB consumed part
  float* h1   = (float*)(ws + OFF_IDX);  // aliases idx: written only after kD consumed idx
  float* out  = (float*)d_out;

  kA<<<dim3(NTILES, NBATCH), 256, 0, stream>>>(coor, region, extents,
                                               w1, b1, w2, b2, w3, b3, part);
  kB<<<dim3(NBATCH), 256, 0, stream>>>(part, xs, idx);
  kC<<<dim3(32, 8), 256, 0, stream>>>(xs, w_sp, Dm);
  kD<<<dim3(NBATCH, 4), 256, 0, stream>>>(Dm, idx, y4);
  kE1<<<dim3(NBATCH, 8), 256, 0, stream>>>(y4, b_sp, fc1_w, fc1_b, h1);
  kE2<<<dim3(NBATCH), 256, 0, stream>>>(h1, fc2_w, fc2_b, fcr_w, fcr_b,
                                        fct_w, fct_b, out);
}

// Round 4
// 228.041 us; speedup vs baseline: 1.3096x; 1.1842x over previous
//
#include <hip/hip_runtime.h>
#include <cstddef>
#include <cstdint>

#define LEAKY(s) ((s) >= 0.f ? (s) : 0.1f * (s))

constexpr int PTS    = 4096;   // H*W
constexpr int NBATCH = 32;
constexpr int NM     = 8;      // regions
constexpr int TILE   = 128;    // points per block in kA
constexpr int NTILES = PTS / TILE;  // 32

// ---------------- workspace layout (bytes) ----------------
// xs   : (B,128,8) f32                     @ 0        (131072)
// idx  : (B,128,8) i32                     @ 131072   (131072)  -- h1 (64KB) aliases after kD
// y4   : (B,4,1024) f32 partial conv_sp    @ 262144   (524288)
// part : (B,NTILES,1024) f32               @ 786432   (4 MB)    -- consumed by kB
// Dm   : (B,128,8,128) f32                 @ 786432   (16 MB)   -- aliases part (written after kB)
constexpr size_t OFF_XS   = 0;
constexpr size_t OFF_IDX  = 131072;
constexpr size_t OFF_Y4   = 262144;
constexpr size_t OFF_PART = 786432;
constexpr size_t OFF_DM   = 786432;

// ============================================================
// Kernel A: fused conv1(5->128) -> conv2 -> conv3 -> region-masked max partials
// grid (NTILES, B), 256 threads, 2 blocks/CU (69.6KB LDS).
// Thread (cg,pg): 8 channels (c0=cg*8) x 8 points split as pl0=pg*4, pl1=64+pg*4.
// LDS rows 128 floats = 512B; each ds_read_b128: 16 lanes cover one contiguous
// 256B chunk (2-way bank aliasing = free), 4 cg groups broadcast same addrs.
// No manual pipelining (R3 showed it bloats VGPR 88->140 and drops occupancy).
// ============================================================
__device__ __forceinline__ void gemm128(const float* __restrict__ W,
                                        const float* act, int c0, int pl0, int pl1,
                                        float acc[8][8]) {
#pragma unroll
  for (int i = 0; i < 8; i++)
#pragma unroll
    for (int j = 0; j < 8; j++) acc[i][j] = 0.f;
  for (int k = 0; k < 128; k += 4) {
    float4 wv[8];
#pragma unroll
    for (int i = 0; i < 8; i++) wv[i] = *(const float4*)(W + (c0 + i) * 128 + k);
    float4 b0[4], b1[4];
#pragma unroll
    for (int kk = 0; kk < 4; kk++) {
      b0[kk] = *(const float4*)(act + (k + kk) * TILE + pl0);
      b1[kk] = *(const float4*)(act + (k + kk) * TILE + pl1);
    }
#pragma unroll
    for (int kk = 0; kk < 4; kk++) {
      float4 q0 = b0[kk], q1 = b1[kk];
      float bv[8] = {q0.x, q0.y, q0.z, q0.w, q1.x, q1.y, q1.z, q1.w};
#pragma unroll
      for (int i = 0; i < 8; i++) {
        float w = (kk == 0) ? wv[i].x : (kk == 1) ? wv[i].y : (kk == 2) ? wv[i].z : wv[i].w;
#pragma unroll
        for (int j = 0; j < 8; j++) acc[i][j] = fmaf(w, bv[j], acc[i][j]);
      }
    }
  }
}

__global__ __launch_bounds__(256) void kA(
    const float* __restrict__ coor, const float* __restrict__ region,
    const float* __restrict__ extents,
    const float* __restrict__ w1, const float* __restrict__ b1,
    const float* __restrict__ w2, const float* __restrict__ b2,
    const float* __restrict__ w3, const float* __restrict__ b3,
    float* __restrict__ part) {
  __shared__ float act[128 * TILE];
  __shared__ float reg_s[NM * TILE];
  const int tid = threadIdx.x;
  const int b = blockIdx.y;
  const int t0 = blockIdx.x * TILE;
  const int cg = tid >> 4, pg = tid & 15;
  const int c0 = cg * 8, pl0 = pg * 4, pl1 = 64 + pg * 4;

  {  // stage region tile: 8 rows x 128 (float4/thread)
    int m = tid >> 5, j = tid & 31;
    float4 v = *(const float4*)(region + ((size_t)b * NM + m) * PTS + t0 + j * 4);
    *(float4*)(reg_s + m * TILE + j * 4) = v;
  }
  {  // layer 1 (K=5) directly from global
    float e0 = extents[b * 3], e1 = extents[b * 3 + 1], e2 = extents[b * 3 + 2];
    float in[5][8];
#pragma unroll
    for (int i = 0; i < 5; i++) {
      float4 a = *(const float4*)(coor + ((size_t)b * 5 + i) * PTS + t0 + pl0);
      float4 c4 = *(const float4*)(coor + ((size_t)b * 5 + i) * PTS + t0 + pl1);
      in[i][0] = a.x;  in[i][1] = a.y;  in[i][2] = a.z;  in[i][3] = a.w;
      in[i][4] = c4.x; in[i][5] = c4.y; in[i][6] = c4.z; in[i][7] = c4.w;
    }
#pragma unroll
    for (int j = 0; j < 8; j++) {
      in[0][j] = (in[0][j] - 0.5f) * e0;
      in[1][j] = (in[1][j] - 0.5f) * e1;
      in[2][j] = (in[2][j] - 0.5f) * e2;
    }
#pragma unroll
    for (int i = 0; i < 8; i++) {
      int c = c0 + i;
      float wA = w1[c * 5], wB = w1[c * 5 + 1], wC = w1[c * 5 + 2],
            wD = w1[c * 5 + 3], wE = w1[c * 5 + 4];
      float bb = b1[c];
      float o[8];
#pragma unroll
      for (int j = 0; j < 8; j++) {
        float s = bb;
        s = fmaf(wA, in[0][j], s); s = fmaf(wB, in[1][j], s); s = fmaf(wC, in[2][j], s);
        s = fmaf(wD, in[3][j], s); s = fmaf(wE, in[4][j], s);
        o[j] = LEAKY(s);
      }
      float4 v0 = {o[0], o[1], o[2], o[3]}, v1 = {o[4], o[5], o[6], o[7]};
      *(float4*)(act + c * TILE + pl0) = v0;
      *(float4*)(act + c * TILE + pl1) = v1;
    }
  }
  __syncthreads();

  float acc[8][8];
  // layer 2
  gemm128(w2, act, c0, pl0, pl1, acc);
  __syncthreads();  // everyone done reading act1
#pragma unroll
  for (int i = 0; i < 8; i++) {
    float bb = b2[c0 + i];
    float o[8];
#pragma unroll
    for (int j = 0; j < 8; j++) { float s = acc[i][j] + bb; o[j] = LEAKY(s); }
    float4 v0 = {o[0], o[1], o[2], o[3]}, v1 = {o[4], o[5], o[6], o[7]};
    *(float4*)(act + (c0 + i) * TILE + pl0) = v0;
    *(float4*)(act + (c0 + i) * TILE + pl1) = v1;
  }
  __syncthreads();
  // layer 3 (no activation)
  gemm128(w3, act, c0, pl0, pl1, acc);
#pragma unroll
  for (int i = 0; i < 8; i++) {
    float bb = b3[c0 + i];
#pragma unroll
    for (int j = 0; j < 8; j++) acc[i][j] += bb;
  }
  __syncthreads();  // all act reads complete; reuse act[0..1023] as store funnel

  // region-masked max over this thread's 8 points, then in-wave reduce over 16 pgroups
#pragma unroll
  for (int m = 0; m < NM; m++) {
    float4 r0 = *(const float4*)(reg_s + m * TILE + pl0);
    float4 r1 = *(const float4*)(reg_s + m * TILE + pl1);
    float rv[8] = {r0.x, r0.y, r0.z, r0.w, r1.x, r1.y, r1.z, r1.w};
#pragma unroll
    for (int i = 0; i < 8; i++) {
      float mx = acc[i][0] * rv[0];
#pragma unroll
      for (int j = 1; j < 8; j++) mx = fmaxf(mx, acc[i][j] * rv[j]);
      mx = fmaxf(mx, __shfl_xor(mx, 1));
      mx = fmaxf(mx, __shfl_xor(mx, 2));
      mx = fmaxf(mx, __shfl_xor(mx, 4));
      mx = fmaxf(mx, __shfl_xor(mx, 8));
      if (pg == 0) act[(c0 + i) * 8 + m] = mx;
    }
  }
  __syncthreads();
  {  // coalesced store: part[b][tile][c*8+m]
    float4 v = *(const float4*)(act + tid * 4);
    *(float4*)(part + ((size_t)b * NTILES + blockIdx.x) * 1024 + tid * 4) = v;
  }
}

// ============================================================
// Kernel B: reduce partials -> pooled (128,8); softmax over channels per m;
// per-(b,c) descending sort of 8 region values -> idx. grid (B), 256 thr.
// part layout: (b, tile, c*8+m) -> stride-1024 reads, coalesced across threads.
// ============================================================
__global__ __launch_bounds__(256) void kB(const float* __restrict__ part,
                                          float* __restrict__ xs,
                                          int* __restrict__ idx) {
  __shared__ float pool[1024];
  __shared__ float xsl[1024];
  int b = blockIdx.x, tid = threadIdx.x;
#pragma unroll
  for (int q = 0; q < 4; q++) {
    int pair = tid + q * 256;
    const float* p = part + (size_t)b * (NTILES * 1024) + pair;
    float mx = p[0];
    for (int t = 1; t < NTILES; t++) mx = fmaxf(mx, p[(size_t)t * 1024]);
    pool[pair] = mx;
  }
  __syncthreads();
  // softmax over the 128 channels, one 32-lane group per m
  int m = tid >> 5, lane = tid & 31;
  float v[4];
#pragma unroll
  for (int j = 0; j < 4; j++) v[j] = pool[(lane + 32 * j) * 8 + m];
  float mx = fmaxf(fmaxf(v[0], v[1]), fmaxf(v[2], v[3]));
#pragma unroll
  for (int d = 1; d < 32; d <<= 1) mx = fmaxf(mx, __shfl_xor(mx, d, 32));
  float e[4]; float s = 0.f;
#pragma unroll
  for (int j = 0; j < 4; j++) { e[j] = expf(v[j] - mx); s += e[j]; }
#pragma unroll
  for (int d = 1; d < 32; d <<= 1) s += __shfl_xor(s, d, 32);
#pragma unroll
  for (int j = 0; j < 4; j++) {
    float x = e[j] / s;
    int c = lane + 32 * j;
    xsl[c * 8 + m] = x;
    xs[(size_t)b * 1024 + c * 8 + m] = x;
  }
  __syncthreads();
  if (tid < 128) {
    float vv[8];
#pragma unroll
    for (int n = 0; n < 8; n++) vv[n] = xsl[tid * 8 + n];
    int used = 0;
#pragma unroll
    for (int n = 0; n < 8; n++) {
      int best = 0; float bvv = -1.f;
#pragma unroll
      for (int q = 0; q < 8; q++) {
        bool ok = ((used >> q) & 1) == 0;
        if (ok && vv[q] > bvv) { bvv = vv[q]; best = q; }  // strict > == lowest-index tie-break
      }
      used |= 1 << best;
      idx[(size_t)b * 1024 + tid * 8 + n] = best;
    }
  }
}

// ============================================================
// Kernel C: D[b,k,m,o] = sum_c xs[b,c,m] * w_sp[o,c,k]
// grid (32 ktiles of 4, 8 bgroups of 4), 256 thr.
// ============================================================
__global__ __launch_bounds__(256) void kC(const float* __restrict__ xs,
                                          const float* __restrict__ w_sp,
                                          float* __restrict__ Dm) {
  __shared__ float As[16 * 512];
  __shared__ float Bs[16 * 32];
  const int tid = threadIdx.x;
  const int k0 = blockIdx.x * 4;
  const int bbase = blockIdx.y * 4;
  const int rg = tid & 63, cgq = tid >> 6;
  const int j0 = cgq * 8;
  float acc[8][8];
#pragma unroll
  for (int i = 0; i < 8; i++)
#pragma unroll
    for (int j = 0; j < 8; j++) acc[i][j] = 0.f;

  for (int c0 = 0; c0 < 128; c0 += 16) {
    __syncthreads();
#pragma unroll
    for (int it = 0; it < 8; it++) {
      int q = tid + it * 256;             // 0..2047
      int o = q >> 4, cc = q & 15;
      float4 w = *(const float4*)(w_sp + (size_t)o * 16384 + (size_t)(c0 + cc) * 128 + k0);
      As[cc * 512 + o]       = w.x;
      As[cc * 512 + 128 + o] = w.y;
      As[cc * 512 + 256 + o] = w.z;
      As[cc * 512 + 384 + o] = w.w;
    }
#pragma unroll
    for (int it = 0; it < 2; it++) {
      int f = tid + it * 256;             // 0..511 = bl*128 + cc*8 + m
      int bl = f >> 7, rem = f & 127;
      Bs[(rem >> 3) * 32 + bl * 8 + (rem & 7)] =
          xs[((size_t)(bbase + bl) * 128 + c0 + (rem >> 3)) * 8 + (rem & 7)];
    }
    __syncthreads();
#pragma unroll
    for (int cc = 0; cc < 16; cc++) {
      float4 a0 = *(const float4*)(As + cc * 512 + rg * 4);
      float4 a1 = *(const float4*)(As + cc * 512 + 256 + rg * 4);
      float4 p0 = *(const float4*)(Bs + cc * 32 + j0);
      float4 p1 = *(const float4*)(Bs + cc * 32 + j0 + 4);
      float av[8] = {a0.x, a0.y, a0.z, a0.w, a1.x, a1.y, a1.z, a1.w};
      float bv[8] = {p0.x, p0.y, p0.z, p0.w, p1.x, p1.y, p1.z, p1.w};
#pragma unroll
      for (int i = 0; i < 8; i++)
#pragma unroll
        for (int j = 0; j < 8; j++) acc[i][j] = fmaf(av[i], bv[j], acc[i][j]);
    }
  }
#pragma unroll
  for (int j = 0; j < 8; j++) {
    int col = j0 + j;
    int bl = col >> 3, m = col & 7, bb = bbase + bl;
    {
      int r = rg * 4;
      int kk = r >> 7, o = r & 127;
      float4 v = {acc[0][j], acc[1][j], acc[2][j], acc[3][j]};
      *(float4*)(Dm + (((size_t)bb * 128 + k0 + kk) * 8 + m) * 128 + o) = v;
    }
    {
      int r = 256 + rg * 4;
      int kk = r >> 7, o = r & 127;
      float4 v = {acc[4][j], acc[5][j], acc[6][j], acc[7][j]};
      *(float4*)(Dm + (((size_t)bb * 128 + k0 + kk) * 8 + m) * 128 + o) = v;
    }
  }
}

// ============================================================
// Kernel D: partial gather-sum y4[b,kq,o*8+r] = sum_{k in kq} D[b,k,idx[b,k,r],o]
// grid (B, 4), 256 thr.
// ============================================================
__global__ __launch_bounds__(256) void kD(const float* __restrict__ Dm,
                                          const int* __restrict__ idx,
                                          float* __restrict__ y4) {
  __shared__ int il[256];  // 32 k x 8 r
  int b = blockIdx.x, kq = blockIdx.y;
  int tid = threadIdx.x;
  il[tid] = idx[(size_t)b * 1024 + kq * 256 + tid];
  __syncthreads();
  int o = tid & 127, half = tid >> 7;
  const float* Db = Dm + (size_t)b * 131072 + (size_t)kq * 32 * 1024;
  float s0 = 0, s1 = 0, s2 = 0, s3 = 0;
  for (int k = 0; k < 32; k++) {
    const float* Dk = Db + k * 1024;
    const int* ik = il + k * 8 + half * 4;
    s0 += Dk[ik[0] * 128 + o];
    s1 += Dk[ik[1] * 128 + o];
    s2 += Dk[ik[2] * 128 + o];
    s3 += Dk[ik[3] * 128 + o];
  }
  float* yo = y4 + ((size_t)b * 4 + kq) * 1024 + o * 8 + half * 4;
  yo[0] = s0; yo[1] = s1; yo[2] = s2; yo[3] = s3;
}

// ============================================================
// Kernel E1: assemble y (sum kq partials + b_sp + leaky), fc1 -> h1.
// grid (B, 8), 256 thr; wave-per-output, coalesced 4KB weight rows.
// ============================================================
__global__ __launch_bounds__(256) void kE1(
    const float* __restrict__ y4, const float* __restrict__ b_sp,
    const float* __restrict__ fc1_w, const float* __restrict__ fc1_b,
    float* __restrict__ h1) {
  __shared__ float yl[1024];
  int b = blockIdx.x, og = blockIdx.y, tid = threadIdx.x;
  {
    int f0 = tid * 4;
    const float* base = y4 + (size_t)b * 4096;
    float4 a0 = *(const float4*)(base + f0);
    float4 a1 = *(const float4*)(base + 1024 + f0);
    float4 a2 = *(const float4*)(base + 2048 + f0);
    float4 a3 = *(const float4*)(base + 3072 + f0);
    float v[4] = {a0.x + a1.x + a2.x + a3.x, a0.y + a1.y + a2.y + a3.y,
                  a0.z + a1.z + a2.z + a3.z, a0.w + a1.w + a2.w + a3.w};
    float o[4];
#pragma unroll
    for (int j = 0; j < 4; j++) {
      int f = f0 + j;
      float s = v[j] + b_sp[f >> 3];
      o[j] = LEAKY(s);
    }
    float4 vv = {o[0], o[1], o[2], o[3]};
    *(float4*)(yl + f0) = vv;
  }
  __syncthreads();
  int wid = tid >> 6, lane = tid & 63;
  const float4* ylv = (const float4*)yl;
#pragma unroll
  for (int pass = 0; pass < 16; pass++) {
    int o = og * 64 + pass * 4 + wid;
    const float4* wr = (const float4*)(fc1_w + (size_t)o * 1024);
    float sa = 0, sb = 0, sc = 0, sd = 0;
#pragma unroll
    for (int r = 0; r < 4; r++) {
      float4 w = wr[r * 64 + lane];
      float4 u = ylv[r * 64 + lane];
      sa = fmaf(w.x, u.x, sa); sb = fmaf(w.y, u.y, sb);
      sc = fmaf(w.z, u.z, sc); sd = fmaf(w.w, u.w, sd);
    }
    float s = (sa + sb) + (sc + sd);
#pragma unroll
    for (int d = 1; d < 64; d <<= 1) s += __shfl_xor(s, d);
    if (lane == 0) {
      float t = s + fc1_b[o];
      h1[(size_t)b * 512 + o] = LEAKY(t);
    }
  }
}

// ============================================================
// Kernel E2: fc2 -> heads. grid (B), 256 thr (thread-per-output fc2).
// ============================================================
__global__ __launch_bounds__(256) void kE2(
    const float* __restrict__ h1, const float* __restrict__ fc2_w,
    const float* __restrict__ fc2_b,
    const float* __restrict__ fcr_w, const float* __restrict__ fcr_b,
    const float* __restrict__ fct_w, const float* __restrict__ fct_b,
    float* __restrict__ out) {
  __shared__ float h1l[512];
  __shared__ float h2[256];
  int b = blockIdx.x, tid = threadIdx.x;
  if (tid < 128) {
    float4 v = *(const float4*)(h1 + (size_t)b * 512 + tid * 4);
    *(float4*)(h1l + tid * 4) = v;
  }
  __syncthreads();
  {
    int o = tid;
    const float4* wr = (const float4*)(fc2_w + (size_t)o * 512);
    const float4* uv = (const float4*)h1l;
    float sa = 0, sb = 0, sc = 0, sd = 0;
#pragma unroll 4
    for (int q = 0; q < 128; q++) {
      float4 w = wr[q];
      float4 u = uv[q];
      sa = fmaf(w.x, u.x, sa); sb = fmaf(w.y, u.y, sb);
      sc = fmaf(w.z, u.z, sc); sd = fmaf(w.w, u.w, sd);
    }
    float s = (sa + sb) + (sc + sd) + fc2_b[o];
    h2[o] = LEAKY(s);
  }
  __syncthreads();
  if (tid < 7) {
    bool isrot = tid < 4;
    int o = isrot ? tid : tid - 4;
    const float4* wr = (const float4*)((isrot ? fcr_w : fct_w) + (size_t)o * 256);
    const float4* uv = (const float4*)h2;
    float sa = 0, sb = 0, sc = 0, sd = 0;
#pragma unroll 4
    for (int q = 0; q < 64; q++) {
      float4 w = wr[q];
      float4 u = uv[q];
      sa = fmaf(w.x, u.x, sa); sb = fmaf(w.y, u.y, sb);
      sc = fmaf(w.z, u.z, sc); sd = fmaf(w.w, u.w, sd);
    }
    float s = (sa + sb) + (sc + sd) + (isrot ? fcr_b[o] : fct_b[o]);
    out[isrot ? (b * 4 + o) : (128 + b * 3 + o)] = s;
  }
}

extern "C" void kernel_launch(void* const* d_in, const int* in_sizes, int n_in,
                              void* d_out, int out_size, void* d_ws, size_t ws_size,
                              hipStream_t stream) {
  const float* coor    = (const float*)d_in[0];
  const float* region  = (const float*)d_in[1];
  const float* extents = (const float*)d_in[2];
  const float* w1 = (const float*)d_in[3];  const float* b1 = (const float*)d_in[4];
  const float* w2 = (const float*)d_in[5];  const float* b2 = (const float*)d_in[6];
  const float* w3 = (const float*)d_in[7];  const float* b3 = (const float*)d_in[8];
  const float* w_sp = (const float*)d_in[9];  const float* b_sp = (const float*)d_in[10];
  const float* fc1_w = (const float*)d_in[11]; const float* fc1_b = (const float*)d_in[12];
  const float* fc2_w = (const float*)d_in[13]; const float* fc2_b = (const float*)d_in[14];
  const float* fcr_w = (const float*)d_in[15]; const float* fcr_b = (const float*)d_in[16];
  const float* fct_w = (const float*)d_in[17]; const float* fct_b = (const float*)d_in[18];

  char* ws = (char*)d_ws;
  float* xs   = (float*)(ws + OFF_XS);
  int*   idx  = (int*)(ws + OFF_IDX);
  float* y4   = (float*)(ws + OFF_Y4);
  float* part = (float*)(ws + OFF_PART);
  float* Dm   = (float*)(ws + OFF_DM);   // aliases part: written only after kB consumed part
  float* h1   = (float*)(ws + OFF_IDX);  // aliases idx: written only after kD consumed idx
  float* out  = (float*)d_out;

  kA<<<dim3(NTILES, NBATCH), 256, 0, stream>>>(coor, region, extents,
                                               w1, b1, w2, b2, w3, b3, part);
  kB<<<dim3(NBATCH), 256, 0, stream>>>(part, xs, idx);
  kC<<<dim3(32, 8), 256, 0, stream>>>(xs, w_sp, Dm);
  kD<<<dim3(NBATCH, 4), 256, 0, stream>>>(Dm, idx, y4);
  kE1<<<dim3(NBATCH, 8), 256, 0, stream>>>(y4, b_sp, fc1_w, fc1_b, h1);
  kE2<<<dim3(NBATCH), 256, 0, stream>>>(h1, fc2_w, fc2_b, fcr_w, fcr_b,
                                        fct_w, fct_b, out);
}

// Round 5
// 160.578 us; speedup vs baseline: 1.8598x; 1.4201x over previous
//
#include <hip/hip_runtime.h>
#include <cstddef>
#include <cstdint>

#define LEAKY(s) ((s) >= 0.f ? (s) : 0.1f * (s))

constexpr int PTS    = 4096;   // H*W
constexpr int NBATCH = 32;
constexpr int NM     = 8;      // regions
constexpr int TILE   = 128;    // points per block in kA
constexpr int NTILES = PTS / TILE;  // 32

// ---------------- workspace layout (bytes) ----------------
constexpr size_t OFF_XS   = 0;         // xs (B,128,8) f32
constexpr size_t OFF_IDX  = 131072;    // idx (B,128,8) i32 ; h1 aliases after kD
constexpr size_t OFF_Y4   = 262144;    // y4 (B,4,1024) f32
constexpr size_t OFF_PART = 786432;    // part (B,NTILES,1024) f32 (4MB), consumed by kB
constexpr size_t OFF_DM   = 786432;    // Dm (B,128,8,128) f32 (16MB), aliases part

using bf16x8 = __attribute__((ext_vector_type(8))) short;
using f32x4v = __attribute__((ext_vector_type(4))) float;
using u16x4  = __attribute__((ext_vector_type(4))) unsigned short;
using u16x8  = __attribute__((ext_vector_type(8))) unsigned short;

// split f32 -> bf16 hi (truncate) + bf16 lo (RNE of remainder): x ~ hi + lo, err ~2^-17
__device__ __forceinline__ void splitbf(float x, unsigned short& h, unsigned short& l) {
  unsigned u = __float_as_uint(x);
  unsigned short hh = (unsigned short)(u >> 16);
  float r = x - __uint_as_float((unsigned)hh << 16);
  unsigned v = __float_as_uint(r);
  unsigned rr = (v + 0x7FFFu + ((v >> 16) & 1u)) >> 16;
  h = hh; l = (unsigned short)rr;
}

// swizzled byte offset into Xt[pt][k] bf16 arrays (row = 256B): XOR bits 4..6 by pt&7
__device__ __forceinline__ int swzb(int pt, int kByte) {
  return pt * 256 + (kByte ^ ((pt & 7) << 4));
}

// ============================================================
// Kernel A: fused conv1(5->128) -> conv2 -> conv3 (split-bf16 MFMA) ->
// region-masked max partials. grid (NTILES, B), 256 thr, 2 blocks/CU.
// Activations in LDS transposed Xt[pt][k] as bf16 hi/lo, XOR-swizzled.
// Wave w owns out-ch rows [32w,32w+32) x all 128 pts (2 m-tiles x 8 n-tiles).
// ============================================================
__device__ __forceinline__ void mfmaLayer(const float* __restrict__ W,
                                          const float* __restrict__ bias,
                                          const char* XHc, const char* XLc,
                                          int lane, int mt0, f32x4v acc[2][8]) {
  const int l15 = lane & 15, l4 = lane >> 4;
#pragma unroll
  for (int mi = 0; mi < 2; mi++) {
    float4 bv = *(const float4*)(bias + (mt0 + mi) * 16 + l4 * 4);
    f32x4v b4; b4[0] = bv.x; b4[1] = bv.y; b4[2] = bv.z; b4[3] = bv.w;
#pragma unroll
    for (int nt = 0; nt < 8; nt++) acc[mi][nt] = b4;
  }
  for (int kt = 0; kt < 4; kt++) {
    bf16x8 ah[2], al[2];
#pragma unroll
    for (int mi = 0; mi < 2; mi++) {
      const float* wp = W + (size_t)((mt0 + mi) * 16 + l15) * 128 + kt * 32 + l4 * 8;
      float4 wa = *(const float4*)wp;
      float4 wb = *(const float4*)(wp + 4);
      float wf[8] = {wa.x, wa.y, wa.z, wa.w, wb.x, wb.y, wb.z, wb.w};
#pragma unroll
      for (int e = 0; e < 8; e++) {
        unsigned short h, l;
        splitbf(wf[e], h, l);
        ah[mi][e] = (short)h; al[mi][e] = (short)l;
      }
    }
    const int kb = (kt * 32 + l4 * 8) * 2;
#pragma unroll
    for (int nt = 0; nt < 8; nt++) {
      const int off = swzb(nt * 16 + l15, kb);
      bf16x8 bh = *(const bf16x8*)(XHc + off);
      bf16x8 bl = *(const bf16x8*)(XLc + off);
#pragma unroll
      for (int mi = 0; mi < 2; mi++) {
        acc[mi][nt] = __builtin_amdgcn_mfma_f32_16x16x32_bf16(ah[mi], bh, acc[mi][nt], 0, 0, 0);
        acc[mi][nt] = __builtin_amdgcn_mfma_f32_16x16x32_bf16(ah[mi], bl, acc[mi][nt], 0, 0, 0);
        acc[mi][nt] = __builtin_amdgcn_mfma_f32_16x16x32_bf16(al[mi], bh, acc[mi][nt], 0, 0, 0);
      }
    }
  }
}

__global__ __launch_bounds__(256, 2) void kA(
    const float* __restrict__ coor, const float* __restrict__ region,
    const float* __restrict__ extents,
    const float* __restrict__ w1, const float* __restrict__ b1,
    const float* __restrict__ w2, const float* __restrict__ b2,
    const float* __restrict__ w3, const float* __restrict__ b3,
    float* __restrict__ part) {
  __shared__ unsigned short XH[128 * 128];  // 32KB  (funnel aliases this in epilogue)
  __shared__ unsigned short XL[128 * 128];  // 32KB
  __shared__ float reg_s[NM * TILE];        // 4KB
  const int tid = threadIdx.x;
  const int b = blockIdx.y;
  const int t0 = blockIdx.x * TILE;
  const int lane = tid & 63;
  const int wv = tid >> 6;
  char* XHc = (char*)XH;
  char* XLc = (char*)XL;

  {  // stage region tile: 8 rows x 128 (float4/thread)
    int m = tid >> 5, j = tid & 31;
    float4 v = *(const float4*)(region + ((size_t)b * NM + m) * PTS + t0 + j * 4);
    *(float4*)(reg_s + m * TILE + j * 4) = v;
  }
  {  // layer 1 (K=5): thread = (pt, ch-half); writes Xt bf16 hi/lo
    const int pt = tid & 127;
    const int chh = (tid >> 7) * 64;
    float e0 = extents[b * 3], e1 = extents[b * 3 + 1], e2 = extents[b * 3 + 2];
    float in5[5];
#pragma unroll
    for (int i = 0; i < 5; i++) in5[i] = coor[((size_t)b * 5 + i) * PTS + t0 + pt];
    in5[0] = (in5[0] - 0.5f) * e0;
    in5[1] = (in5[1] - 0.5f) * e1;
    in5[2] = (in5[2] - 0.5f) * e2;
    for (int c8 = 0; c8 < 64; c8 += 8) {
      u16x8 hh, ll;
#pragma unroll
      for (int q = 0; q < 8; q++) {
        int c = chh + c8 + q;
        float s = b1[c];
#pragma unroll
        for (int i = 0; i < 5; i++) s = fmaf(w1[c * 5 + i], in5[i], s);
        s = LEAKY(s);
        unsigned short h, l;
        splitbf(s, h, l);
        hh[q] = h; ll[q] = l;
      }
      int off = swzb(pt, (chh + c8) * 2);
      *(u16x8*)(XHc + off) = hh;
      *(u16x8*)(XLc + off) = ll;
    }
  }
  __syncthreads();

  f32x4v acc[2][8];
  const int mt0 = wv * 2;
  const int l15 = lane & 15, l4 = lane >> 4;

  // layer 2
  mfmaLayer(w2, b2, XHc, XLc, lane, mt0, acc);
  __syncthreads();  // all layer-2 reads of Xt complete
  {                 // leaky + split + write act2 back to Xt
#pragma unroll
    for (int mi = 0; mi < 2; mi++) {
      const int ch0 = (mt0 + mi) * 16 + l4 * 4;
#pragma unroll
      for (int nt = 0; nt < 8; nt++) {
        u16x4 h4, l4v;
#pragma unroll
        for (int r = 0; r < 4; r++) {
          float s = acc[mi][nt][r];
          s = LEAKY(s);
          unsigned short h, l;
          splitbf(s, h, l);
          h4[r] = h; l4v[r] = l;
        }
        int off = swzb(nt * 16 + l15, ch0 * 2);
        *(u16x4*)(XHc + off) = h4;
        *(u16x4*)(XLc + off) = l4v;
      }
    }
  }
  __syncthreads();
  // layer 3 (bias, no activation)
  mfmaLayer(w3, b3, XHc, XLc, lane, mt0, acc);
  __syncthreads();  // all layer-3 reads done; reuse XH as f32 funnel

  {  // region-masked max epilogue
    float* funnel = (float*)XH;
#pragma unroll
    for (int m = 0; m < NM; m++) {
      float rv[8];
#pragma unroll
      for (int nt = 0; nt < 8; nt++) rv[nt] = reg_s[m * TILE + nt * 16 + l15];
#pragma unroll
      for (int mi = 0; mi < 2; mi++)
#pragma unroll
        for (int r = 0; r < 4; r++) {
          float mx = acc[mi][0][r] * rv[0];
#pragma unroll
          for (int nt = 1; nt < 8; nt++) mx = fmaxf(mx, acc[mi][nt][r] * rv[nt]);
          mx = fmaxf(mx, __shfl_xor(mx, 1));
          mx = fmaxf(mx, __shfl_xor(mx, 2));
          mx = fmaxf(mx, __shfl_xor(mx, 4));
          mx = fmaxf(mx, __shfl_xor(mx, 8));
          if (l15 == 0) funnel[((mt0 + mi) * 16 + l4 * 4 + r) * 8 + m] = mx;
        }
    }
  }
  __syncthreads();
  {  // coalesced store: part[b][tile][c*8+m]
    float4 v = *(const float4*)((float*)XH + tid * 4);
    *(float4*)(part + ((size_t)b * NTILES + blockIdx.x) * 1024 + tid * 4) = v;
  }
}

// ============================================================
// Kernel B: reduce partials -> pooled (128,8); softmax over channels per m;
// per-(b,c) descending sort of 8 region values -> idx. grid (B), 256 thr.
// ============================================================
__global__ __launch_bounds__(256) void kB(const float* __restrict__ part,
                                          float* __restrict__ xs,
                                          int* __restrict__ idx) {
  __shared__ float pool[1024];
  __shared__ float xsl[1024];
  int b = blockIdx.x, tid = threadIdx.x;
#pragma unroll
  for (int q = 0; q < 4; q++) {
    int pair = tid + q * 256;
    const float* p = part + (size_t)b * (NTILES * 1024) + pair;
    float mx = p[0];
    for (int t = 1; t < NTILES; t++) mx = fmaxf(mx, p[(size_t)t * 1024]);
    pool[pair] = mx;
  }
  __syncthreads();
  int m = tid >> 5, lane = tid & 31;
  float v[4];
#pragma unroll
  for (int j = 0; j < 4; j++) v[j] = pool[(lane + 32 * j) * 8 + m];
  float mx = fmaxf(fmaxf(v[0], v[1]), fmaxf(v[2], v[3]));
#pragma unroll
  for (int d = 1; d < 32; d <<= 1) mx = fmaxf(mx, __shfl_xor(mx, d, 32));
  float e[4]; float s = 0.f;
#pragma unroll
  for (int j = 0; j < 4; j++) { e[j] = expf(v[j] - mx); s += e[j]; }
#pragma unroll
  for (int d = 1; d < 32; d <<= 1) s += __shfl_xor(s, d, 32);
#pragma unroll
  for (int j = 0; j < 4; j++) {
    float x = e[j] / s;
    int c = lane + 32 * j;
    xsl[c * 8 + m] = x;
    xs[(size_t)b * 1024 + c * 8 + m] = x;
  }
  __syncthreads();
  if (tid < 128) {
    float vv[8];
#pragma unroll
    for (int n = 0; n < 8; n++) vv[n] = xsl[tid * 8 + n];
    int used = 0;
#pragma unroll
    for (int n = 0; n < 8; n++) {
      int best = 0; float bvv = -1.f;
#pragma unroll
      for (int q = 0; q < 8; q++) {
        bool ok = ((used >> q) & 1) == 0;
        if (ok && vv[q] > bvv) { bvv = vv[q]; best = q; }  // strict > == lowest-index tie-break
      }
      used |= 1 << best;
      idx[(size_t)b * 1024 + tid * 8 + n] = best;
    }
  }
}

// ============================================================
// Kernel C: D[b,k,m,o] = sum_c xs[b,c,m] * w_sp[o,c,k]
// grid (32 ktiles of 4, 8 bgroups of 4), 256 thr.
// ============================================================
__global__ __launch_bounds__(256) void kC(const float* __restrict__ xs,
                                          const float* __restrict__ w_sp,
                                          float* __restrict__ Dm) {
  __shared__ float As[16 * 512];
  __shared__ float Bs[16 * 32];
  const int tid = threadIdx.x;
  const int k0 = blockIdx.x * 4;
  const int bbase = blockIdx.y * 4;
  const int rg = tid & 63, cgq = tid >> 6;
  const int j0 = cgq * 8;
  float acc[8][8];
#pragma unroll
  for (int i = 0; i < 8; i++)
#pragma unroll
    for (int j = 0; j < 8; j++) acc[i][j] = 0.f;

  for (int c0 = 0; c0 < 128; c0 += 16) {
    __syncthreads();
#pragma unroll
    for (int it = 0; it < 8; it++) {
      int q = tid + it * 256;
      int o = q >> 4, cc = q & 15;
      float4 w = *(const float4*)(w_sp + (size_t)o * 16384 + (size_t)(c0 + cc) * 128 + k0);
      As[cc * 512 + o]       = w.x;
      As[cc * 512 + 128 + o] = w.y;
      As[cc * 512 + 256 + o] = w.z;
      As[cc * 512 + 384 + o] = w.w;
    }
#pragma unroll
    for (int it = 0; it < 2; it++) {
      int f = tid + it * 256;
      int bl = f >> 7, rem = f & 127;
      Bs[(rem >> 3) * 32 + bl * 8 + (rem & 7)] =
          xs[((size_t)(bbase + bl) * 128 + c0 + (rem >> 3)) * 8 + (rem & 7)];
    }
    __syncthreads();
#pragma unroll
    for (int cc = 0; cc < 16; cc++) {
      float4 a0 = *(const float4*)(As + cc * 512 + rg * 4);
      float4 a1 = *(const float4*)(As + cc * 512 + 256 + rg * 4);
      float4 p0 = *(const float4*)(Bs + cc * 32 + j0);
      float4 p1 = *(const float4*)(Bs + cc * 32 + j0 + 4);
      float av[8] = {a0.x, a0.y, a0.z, a0.w, a1.x, a1.y, a1.z, a1.w};
      float bv[8] = {p0.x, p0.y, p0.z, p0.w, p1.x, p1.y, p1.z, p1.w};
#pragma unroll
      for (int i = 0; i < 8; i++)
#pragma unroll
        for (int j = 0; j < 8; j++) acc[i][j] = fmaf(av[i], bv[j], acc[i][j]);
    }
  }
#pragma unroll
  for (int j = 0; j < 8; j++) {
    int col = j0 + j;
    int bl = col >> 3, m = col & 7, bb = bbase + bl;
    {
      int r = rg * 4;
      int kk = r >> 7, o = r & 127;
      float4 v = {acc[0][j], acc[1][j], acc[2][j], acc[3][j]};
      *(float4*)(Dm + (((size_t)bb * 128 + k0 + kk) * 8 + m) * 128 + o) = v;
    }
    {
      int r = 256 + rg * 4;
      int kk = r >> 7, o = r & 127;
      float4 v = {acc[4][j], acc[5][j], acc[6][j], acc[7][j]};
      *(float4*)(Dm + (((size_t)bb * 128 + k0 + kk) * 8 + m) * 128 + o) = v;
    }
  }
}

// ============================================================
// Kernel D: y4[b,kq,o*8+r] = sum_{k in kq} D[b,k,idx[b,k,r],o]. grid (B,4).
// ============================================================
__global__ __launch_bounds__(256) void kD(const float* __restrict__ Dm,
                                          const int* __restrict__ idx,
                                          float* __restrict__ y4) {
  __shared__ int il[256];
  int b = blockIdx.x, kq = blockIdx.y;
  int tid = threadIdx.x;
  il[tid] = idx[(size_t)b * 1024 + kq * 256 + tid];
  __syncthreads();
  int o = tid & 127, half = tid >> 7;
  const float* Db = Dm + (size_t)b * 131072 + (size_t)kq * 32 * 1024;
  float s0 = 0, s1 = 0, s2 = 0, s3 = 0;
  for (int k = 0; k < 32; k++) {
    const float* Dk = Db + k * 1024;
    const int* ik = il + k * 8 + half * 4;
    s0 += Dk[ik[0] * 128 + o];
    s1 += Dk[ik[1] * 128 + o];
    s2 += Dk[ik[2] * 128 + o];
    s3 += Dk[ik[3] * 128 + o];
  }
  float* yo = y4 + ((size_t)b * 4 + kq) * 1024 + o * 8 + half * 4;
  yo[0] = s0; yo[1] = s1; yo[2] = s2; yo[3] = s3;
}

// ============================================================
// Kernel E1: assemble y, fc1 -> h1. grid (B, 8), 256 thr.
// ============================================================
__global__ __launch_bounds__(256) void kE1(
    const float* __restrict__ y4, const float* __restrict__ b_sp,
    const float* __restrict__ fc1_w, const float* __restrict__ fc1_b,
    float* __restrict__ h1) {
  __shared__ float yl[1024];
  int b = blockIdx.x, og = blockIdx.y, tid = threadIdx.x;
  {
    int f0 = tid * 4;
    const float* base = y4 + (size_t)b * 4096;
    float4 a0 = *(const float4*)(base + f0);
    float4 a1 = *(const float4*)(base + 1024 + f0);
    float4 a2 = *(const float4*)(base + 2048 + f0);
    float4 a3 = *(const float4*)(base + 3072 + f0);
    float v[4] = {a0.x + a1.x + a2.x + a3.x, a0.y + a1.y + a2.y + a3.y,
                  a0.z + a1.z + a2.z + a3.z, a0.w + a1.w + a2.w + a3.w};
    float o[4];
#pragma unroll
    for (int j = 0; j < 4; j++) {
      int f = f0 + j;
      float s = v[j] + b_sp[f >> 3];
      o[j] = LEAKY(s);
    }
    float4 vv = {o[0], o[1], o[2], o[3]};
    *(float4*)(yl + f0) = vv;
  }
  __syncthreads();
  int wid = tid >> 6, lane = tid & 63;
  const float4* ylv = (const float4*)yl;
#pragma unroll
  for (int pass = 0; pass < 16; pass++) {
    int o = og * 64 + pass * 4 + wid;
    const float4* wr = (const float4*)(fc1_w + (size_t)o * 1024);
    float sa = 0, sb = 0, sc = 0, sd = 0;
#pragma unroll
    for (int r = 0; r < 4; r++) {
      float4 w = wr[r * 64 + lane];
      float4 u = ylv[r * 64 + lane];
      sa = fmaf(w.x, u.x, sa); sb = fmaf(w.y, u.y, sb);
      sc = fmaf(w.z, u.z, sc); sd = fmaf(w.w, u.w, sd);
    }
    float s = (sa + sb) + (sc + sd);
#pragma unroll
    for (int d = 1; d < 64; d <<= 1) s += __shfl_xor(s, d);
    if (lane == 0) {
      float t = s + fc1_b[o];
      h1[(size_t)b * 512 + o] = LEAKY(t);
    }
  }
}

// ============================================================
// Kernel E2: fc2 -> heads. grid (B), 256 thr.
// ============================================================
__global__ __launch_bounds__(256) void kE2(
    const float* __restrict__ h1, const float* __restrict__ fc2_w,
    const float* __restrict__ fc2_b,
    const float* __restrict__ fcr_w, const float* __restrict__ fcr_b,
    const float* __restrict__ fct_w, const float* __restrict__ fct_b,
    float* __restrict__ out) {
  __shared__ float h1l[512];
  __shared__ float h2[256];
  int b = blockIdx.x, tid = threadIdx.x;
  if (tid < 128) {
    float4 v = *(const float4*)(h1 + (size_t)b * 512 + tid * 4);
    *(float4*)(h1l + tid * 4) = v;
  }
  __syncthreads();
  {
    int o = tid;
    const float4* wr = (const float4*)(fc2_w + (size_t)o * 512);
    const float4* uv = (const float4*)h1l;
    float sa = 0, sb = 0, sc = 0, sd = 0;
#pragma unroll 4
    for (int q = 0; q < 128; q++) {
      float4 w = wr[q];
      float4 u = uv[q];
      sa = fmaf(w.x, u.x, sa); sb = fmaf(w.y, u.y, sb);
      sc = fmaf(w.z, u.z, sc); sd = fmaf(w.w, u.w, sd);
    }
    float s = (sa + sb) + (sc + sd) + fc2_b[o];
    h2[o] = LEAKY(s);
  }
  __syncthreads();
  if (tid < 7) {
    bool isrot = tid < 4;
    int o = isrot ? tid : tid - 4;
    const float4* wr = (const float4*)((isrot ? fcr_w : fct_w) + (size_t)o * 256);
    const float4* uv = (const float4*)h2;
    float sa = 0, sb = 0, sc = 0, sd = 0;
#pragma unroll 4
    for (int q = 0; q < 64; q++) {
      float4 w = wr[q];
      float4 u = uv[q];
      sa = fmaf(w.x, u.x, sa); sb = fmaf(w.y, u.y, sb);
      sc = fmaf(w.z, u.z, sc); sd = fmaf(w.w, u.w, sd);
    }
    float s = (sa + sb) + (sc + sd) + (isrot ? fcr_b[o] : fct_b[o]);
    out[isrot ? (b * 4 + o) : (128 + b * 3 + o)] = s;
  }
}

extern "C" void kernel_launch(void* const* d_in, const int* in_sizes, int n_in,
                              void* d_out, int out_size, void* d_ws, size_t ws_size,
                              hipStream_t stream) {
  const float* coor    = (const float*)d_in[0];
  const float* region  = (const float*)d_in[1];
  const float* extents = (const float*)d_in[2];
  const float* w1 = (const float*)d_in[3];  const float* b1 = (const float*)d_in[4];
  const float* w2 = (const float*)d_in[5];  const float* b2 = (const float*)d_in[6];
  const float* w3 = (const float*)d_in[7];  const float* b3 = (const float*)d_in[8];
  const float* w_sp = (const float*)d_in[9];  const float* b_sp = (const float*)d_in[10];
  const float* fc1_w = (const float*)d_in[11]; const float* fc1_b = (const float*)d_in[12];
  const float* fc2_w = (const float*)d_in[13]; const float* fc2_b = (const float*)d_in[14];
  const float* fcr_w = (const float*)d_in[15]; const float* fcr_b = (const float*)d_in[16];
  const float* fct_w = (const float*)d_in[17]; const float* fct_b = (const float*)d_in[18];

  char* ws = (char*)d_ws;
  float* xs   = (float*)(ws + OFF_XS);
  int*   idx  = (int*)(ws + OFF_IDX);
  float* y4   = (float*)(ws + OFF_Y4);
  float* part = (float*)(ws + OFF_PART);
  float* Dm   = (float*)(ws + OFF_DM);   // aliases part: written only after kB consumed part
  float* h1   = (float*)(ws + OFF_IDX);  // aliases idx: written only after kD consumed idx
  float* out  = (float*)d_out;

  kA<<<dim3(NTILES, NBATCH), 256, 0, stream>>>(coor, region, extents,
                                               w1, b1, w2, b2, w3, b3, part);
  kB<<<dim3(NBATCH), 256, 0, stream>>>(part, xs, idx);
  kC<<<dim3(32, 8), 256, 0, stream>>>(xs, w_sp, Dm);
  kD<<<dim3(NBATCH, 4), 256, 0, stream>>>(Dm, idx, y4);
  kE1<<<dim3(NBATCH, 8), 256, 0, stream>>>(y4, b_sp, fc1_w, fc1_b, h1);
  kE2<<<dim3(NBATCH), 256, 0, stream>>>(h1, fc2_w, fc2_b, fcr_w, fcr_b,
                                        fct_w, fct_b, out);
}

// Round 6
// 155.027 us; speedup vs baseline: 1.9264x; 1.0358x over previous
//
#include <hip/hip_runtime.h>
#include <cstddef>
#include <cstdint>

#define LEAKY(s) ((s) >= 0.f ? (s) : 0.1f * (s))

constexpr int PTS    = 4096;   // H*W
constexpr int NBATCH = 32;
constexpr int NM     = 8;      // regions
constexpr int TILE   = 128;    // points per block in kA
constexpr int NTILES = PTS / TILE;  // 32

// ---------------- workspace layout (bytes) ----------------
constexpr size_t OFF_XS   = 0;        // xs  (B,128,8) f32           128KB
constexpr size_t OFF_IDX  = 131072;   // idx (B,128,8) i32           128KB ; h1 aliases after kC
constexpr size_t OFF_POOL = 262144;   // pool(B,1024) u32 (enc f32)  128KB
constexpr size_t OFF_WSP  = 393216;   // split weights w2h/w2l/w3h/w3l  128KB
constexpr size_t OFF_Y32  = 524288;   // y32 (B,32,1024) f32         4MB

using bf16x8 = __attribute__((ext_vector_type(8))) short;
using f32x4v = __attribute__((ext_vector_type(4))) float;
using u16x4  = __attribute__((ext_vector_type(4))) unsigned short;
using u16x8  = __attribute__((ext_vector_type(8))) unsigned short;

// split f32 -> bf16 hi (truncate) + bf16 lo (RNE of remainder): x ~ hi + lo
__device__ __forceinline__ void splitbf(float x, unsigned short& h, unsigned short& l) {
  unsigned u = __float_as_uint(x);
  unsigned short hh = (unsigned short)(u >> 16);
  float r = x - __uint_as_float((unsigned)hh << 16);
  unsigned v = __float_as_uint(r);
  unsigned rr = (v + 0x7FFFu + ((v >> 16) & 1u)) >> 16;
  h = hh; l = (unsigned short)rr;
}

// monotone f32 -> u32 encoding (order-preserving) for atomicMax pooling
__device__ __forceinline__ unsigned encf(float f) {
  unsigned u = __float_as_uint(f);
  return (u & 0x80000000u) ? ~u : (u | 0x80000000u);
}
__device__ __forceinline__ float decf(unsigned e) {
  unsigned u = (e & 0x80000000u) ? (e ^ 0x80000000u) : ~e;
  return __uint_as_float(u);
}

// swizzled byte offset into Xt[pt][k] bf16 arrays (row = 256B): XOR bits 4..6 by pt&7
__device__ __forceinline__ int swzb(int pt, int kByte) {
  return pt * 256 + (kByte ^ ((pt & 7) << 4));
}

// ============================================================
// Kernel W: pre-split w2/w3 into bf16 hi/lo planes, laid out in A-fragment
// order: elem index = (((mt*4+kt)*4+l4)*16+l15)*8+e ; c=mt*16+l15, k=kt*32+l4*8+e
// planes: [layer][hi 16384][lo 16384] u16. grid(128),256.
// ============================================================
__global__ __launch_bounds__(256) void kW(const float* __restrict__ w2,
                                          const float* __restrict__ w3,
                                          unsigned short* __restrict__ wsp) {
  int id = blockIdx.x * 256 + threadIdx.x;   // 0..32767
  int layer = id >> 14, e16 = id & 16383;
  int e = e16 & 7, l15 = (e16 >> 3) & 15, l4 = (e16 >> 7) & 3,
      kt = (e16 >> 9) & 3, mt = e16 >> 11;
  int c = mt * 16 + l15, k = kt * 32 + l4 * 8 + e;
  float v = (layer ? w3 : w2)[c * 128 + k];
  unsigned short h, l;
  splitbf(v, h, l);
  wsp[layer * 32768 + e16] = h;
  wsp[layer * 32768 + 16384 + e16] = l;
}

// ============================================================
// Kernel A: fused conv1 -> conv2 -> conv3 (split-bf16 MFMA) -> masked-max
// -> atomicMax pool. grid (NTILES, B), 256 thr, 2 blocks/CU.
// ============================================================
__device__ __forceinline__ void mfmaLayer(const unsigned short* __restrict__ Wh,
                                          const unsigned short* __restrict__ Wl,
                                          const float* __restrict__ bias,
                                          const char* XHc, const char* XLc,
                                          int lane, int mt0, f32x4v acc[2][8]) {
  const int l15 = lane & 15, l4 = lane >> 4;
#pragma unroll
  for (int mi = 0; mi < 2; mi++) {
    float4 bv = *(const float4*)(bias + (mt0 + mi) * 16 + l4 * 4);
    f32x4v b4; b4[0] = bv.x; b4[1] = bv.y; b4[2] = bv.z; b4[3] = bv.w;
#pragma unroll
    for (int nt = 0; nt < 8; nt++) acc[mi][nt] = b4;
  }
#pragma unroll
  for (int kt = 0; kt < 4; kt++) {
    bf16x8 ah[2], al[2];
#pragma unroll
    for (int mi = 0; mi < 2; mi++) {
      int off = ((((mt0 + mi) * 4 + kt) * 4 + l4) * 16 + l15) * 8;
      ah[mi] = *(const bf16x8*)(Wh + off);
      al[mi] = *(const bf16x8*)(Wl + off);
    }
    const int kb = (kt * 32 + l4 * 8) * 2;
#pragma unroll
    for (int nt = 0; nt < 8; nt++) {
      const int off = swzb(nt * 16 + l15, kb);
      bf16x8 bh = *(const bf16x8*)(XHc + off);
      bf16x8 bl = *(const bf16x8*)(XLc + off);
#pragma unroll
      for (int mi = 0; mi < 2; mi++) {
        acc[mi][nt] = __builtin_amdgcn_mfma_f32_16x16x32_bf16(ah[mi], bh, acc[mi][nt], 0, 0, 0);
        acc[mi][nt] = __builtin_amdgcn_mfma_f32_16x16x32_bf16(ah[mi], bl, acc[mi][nt], 0, 0, 0);
        acc[mi][nt] = __builtin_amdgcn_mfma_f32_16x16x32_bf16(al[mi], bh, acc[mi][nt], 0, 0, 0);
      }
    }
  }
}

__global__ __launch_bounds__(256, 2) void kA(
    const float* __restrict__ coor, const float* __restrict__ region,
    const float* __restrict__ extents,
    const float* __restrict__ w1, const float* __restrict__ b1,
    const float* __restrict__ b2, const float* __restrict__ b3,
    const unsigned short* __restrict__ wsp,
    unsigned* __restrict__ pool) {
  __shared__ unsigned short XH[128 * 128];  // 32KB (funnel aliases in epilogue)
  __shared__ unsigned short XL[128 * 128];  // 32KB
  __shared__ float reg_s[NM * TILE];        // 4KB
  const int tid = threadIdx.x;
  const int b = blockIdx.y;
  const int t0 = blockIdx.x * TILE;
  const int lane = tid & 63;
  const int wv = tid >> 6;
  char* XHc = (char*)XH;
  char* XLc = (char*)XL;

  {  // stage region tile: 8 rows x 128
    int m = tid >> 5, j = tid & 31;
    float4 v = *(const float4*)(region + ((size_t)b * NM + m) * PTS + t0 + j * 4);
    *(float4*)(reg_s + m * TILE + j * 4) = v;
  }
  {  // layer 1 (K=5): thread = (pt, ch-half); writes Xt bf16 hi/lo
    const int pt = tid & 127;
    const int chh = (tid >> 7) * 64;
    float e0 = extents[b * 3], e1 = extents[b * 3 + 1], e2 = extents[b * 3 + 2];
    float in5[5];
#pragma unroll
    for (int i = 0; i < 5; i++) in5[i] = coor[((size_t)b * 5 + i) * PTS + t0 + pt];
    in5[0] = (in5[0] - 0.5f) * e0;
    in5[1] = (in5[1] - 0.5f) * e1;
    in5[2] = (in5[2] - 0.5f) * e2;
    for (int c8 = 0; c8 < 64; c8 += 8) {
      u16x8 hh, ll;
#pragma unroll
      for (int q = 0; q < 8; q++) {
        int c = chh + c8 + q;
        float s = b1[c];
#pragma unroll
        for (int i = 0; i < 5; i++) s = fmaf(w1[c * 5 + i], in5[i], s);
        s = LEAKY(s);
        unsigned short h, l;
        splitbf(s, h, l);
        hh[q] = h; ll[q] = l;
      }
      int off = swzb(pt, (chh + c8) * 2);
      *(u16x8*)(XHc + off) = hh;
      *(u16x8*)(XLc + off) = ll;
    }
  }
  __syncthreads();

  f32x4v acc[2][8];
  const int mt0 = wv * 2;
  const int l15 = lane & 15, l4 = lane >> 4;

  // layer 2
  mfmaLayer(wsp, wsp + 16384, b2, XHc, XLc, lane, mt0, acc);
  __syncthreads();
  {  // leaky + split + write act2 back to Xt
#pragma unroll
    for (int mi = 0; mi < 2; mi++) {
      const int ch0 = (mt0 + mi) * 16 + l4 * 4;
#pragma unroll
      for (int nt = 0; nt < 8; nt++) {
        u16x4 h4, l4v;
#pragma unroll
        for (int r = 0; r < 4; r++) {
          float s = acc[mi][nt][r];
          s = LEAKY(s);
          unsigned short h, l;
          splitbf(s, h, l);
          h4[r] = h; l4v[r] = l;
        }
        int off = swzb(nt * 16 + l15, ch0 * 2);
        *(u16x4*)(XHc + off) = h4;
        *(u16x4*)(XLc + off) = l4v;
      }
    }
  }
  __syncthreads();
  // layer 3 (bias, no activation)
  mfmaLayer(wsp + 32768, wsp + 49152, b3, XHc, XLc, lane, mt0, acc);
  __syncthreads();  // all reads done; reuse XH as f32 funnel

  {  // region-masked max -> funnel[c*8+m]
    float* funnel = (float*)XH;
#pragma unroll
    for (int m = 0; m < NM; m++) {
      float rv[8];
#pragma unroll
      for (int nt = 0; nt < 8; nt++) rv[nt] = reg_s[m * TILE + nt * 16 + l15];
#pragma unroll
      for (int mi = 0; mi < 2; mi++)
#pragma unroll
        for (int r = 0; r < 4; r++) {
          float mx = acc[mi][0][r] * rv[0];
#pragma unroll
          for (int nt = 1; nt < 8; nt++) mx = fmaxf(mx, acc[mi][nt][r] * rv[nt]);
          mx = fmaxf(mx, __shfl_xor(mx, 1));
          mx = fmaxf(mx, __shfl_xor(mx, 2));
          mx = fmaxf(mx, __shfl_xor(mx, 4));
          mx = fmaxf(mx, __shfl_xor(mx, 8));
          if (l15 == 0) funnel[((mt0 + mi) * 16 + l4 * 4 + r) * 8 + m] = mx;
        }
    }
  }
  __syncthreads();
  {  // order-independent pool: atomicMax of monotone-encoded f32
    const float* fun = (const float*)XH;
    float4 v = *(const float4*)(fun + tid * 4);
    unsigned* pl = pool + (size_t)b * 1024 + tid * 4;
    atomicMax(pl + 0, encf(v.x));
    atomicMax(pl + 1, encf(v.y));
    atomicMax(pl + 2, encf(v.z));
    atomicMax(pl + 3, encf(v.w));
  }
}

// ============================================================
// Kernel B: decode pool -> softmax over channels per m -> per-(b,c) sort.
// grid (B), 256 thr.
// ============================================================
__global__ __launch_bounds__(256) void kB(const unsigned* __restrict__ pool,
                                          float* __restrict__ xs,
                                          int* __restrict__ idx) {
  __shared__ float pl[1024];
  __shared__ float xsl[1024];
  int b = blockIdx.x, tid = threadIdx.x;
#pragma unroll
  for (int q = 0; q < 4; q++) {
    int p = tid + q * 256;
    pl[p] = decf(pool[(size_t)b * 1024 + p]);
  }
  __syncthreads();
  int m = tid >> 5, lane = tid & 31;
  float v[4];
#pragma unroll
  for (int j = 0; j < 4; j++) v[j] = pl[(lane + 32 * j) * 8 + m];
  float mx = fmaxf(fmaxf(v[0], v[1]), fmaxf(v[2], v[3]));
#pragma unroll
  for (int d = 1; d < 32; d <<= 1) mx = fmaxf(mx, __shfl_xor(mx, d, 32));
  float e[4]; float s = 0.f;
#pragma unroll
  for (int j = 0; j < 4; j++) { e[j] = expf(v[j] - mx); s += e[j]; }
#pragma unroll
  for (int d = 1; d < 32; d <<= 1) s += __shfl_xor(s, d, 32);
#pragma unroll
  for (int j = 0; j < 4; j++) {
    float x = e[j] / s;
    int c = lane + 32 * j;
    xsl[c * 8 + m] = x;
    xs[(size_t)b * 1024 + c * 8 + m] = x;
  }
  __syncthreads();
  if (tid < 128) {
    float vv[8];
#pragma unroll
    for (int n = 0; n < 8; n++) vv[n] = xsl[tid * 8 + n];
    int used = 0;
#pragma unroll
    for (int n = 0; n < 8; n++) {
      int best = 0; float bvv = -1.f;
#pragma unroll
      for (int q = 0; q < 8; q++) {
        bool ok = ((used >> q) & 1) == 0;
        if (ok && vv[q] > bvv) { bvv = vv[q]; best = q; }  // strict > == lowest-index tie-break
      }
      used |= 1 << best;
      idx[(size_t)b * 1024 + tid * 8 + n] = best;
    }
  }
}

// ============================================================
// Kernel C: GEMM D[b,k,m,o] = sum_c xs[b,c,m]*w_sp[o,c,k], fused gather-sum
// epilogue: y32[b][ktile][o*8+r] = sum_{k in ktile} D[b,k,idx[b,k,r],o].
// grid (32 ktiles of 4, 8 bgroups of 4), 256 thr.
// ============================================================
__global__ __launch_bounds__(256) void kC(const float* __restrict__ xs,
                                          const float* __restrict__ w_sp,
                                          const int* __restrict__ idx,
                                          float* __restrict__ y32) {
  __shared__ float As[16 * 512];
  __shared__ float Bs[16 * 32];
  __shared__ int idxL[4][4][8];  // [bl][kk][r]
  const int tid = threadIdx.x;
  const int k0 = blockIdx.x * 4;
  const int bbase = blockIdx.y * 4;
  const int rg = tid & 63, cgq = tid >> 6;
  const int j0 = cgq * 8;
  if (tid < 128) {
    int bl = tid >> 5, kk = (tid >> 3) & 3, r = tid & 7;
    idxL[bl][kk][r] = idx[(size_t)(bbase + bl) * 1024 + (k0 + kk) * 8 + r];
  }
  float acc[8][8];
#pragma unroll
  for (int i = 0; i < 8; i++)
#pragma unroll
    for (int j = 0; j < 8; j++) acc[i][j] = 0.f;

  for (int c0 = 0; c0 < 128; c0 += 16) {
    __syncthreads();
#pragma unroll
    for (int it = 0; it < 8; it++) {
      int q = tid + it * 256;
      int o = q >> 4, cc = q & 15;
      float4 w = *(const float4*)(w_sp + (size_t)o * 16384 + (size_t)(c0 + cc) * 128 + k0);
      As[cc * 512 + o]       = w.x;
      As[cc * 512 + 128 + o] = w.y;
      As[cc * 512 + 256 + o] = w.z;
      As[cc * 512 + 384 + o] = w.w;
    }
#pragma unroll
    for (int it = 0; it < 2; it++) {
      int f = tid + it * 256;
      int bl = f >> 7, rem = f & 127;
      Bs[(rem >> 3) * 32 + bl * 8 + (rem & 7)] =
          xs[((size_t)(bbase + bl) * 128 + c0 + (rem >> 3)) * 8 + (rem & 7)];
    }
    __syncthreads();
#pragma unroll
    for (int cc = 0; cc < 16; cc++) {
      float4 a0 = *(const float4*)(As + cc * 512 + rg * 4);
      float4 a1 = *(const float4*)(As + cc * 512 + 256 + rg * 4);
      float4 p0 = *(const float4*)(Bs + cc * 32 + j0);
      float4 p1 = *(const float4*)(Bs + cc * 32 + j0 + 4);
      float av[8] = {a0.x, a0.y, a0.z, a0.w, a1.x, a1.y, a1.z, a1.w};
      float bv[8] = {p0.x, p0.y, p0.z, p0.w, p1.x, p1.y, p1.z, p1.w};
#pragma unroll
      for (int i = 0; i < 8; i++)
#pragma unroll
        for (int j = 0; j < 8; j++) acc[i][j] = fmaf(av[i], bv[j], acc[i][j]);
    }
  }
  // gather-sum epilogue. acc rows: i<4 -> row rg*4+i (kk = rg>>5, o=(rg&31)*4+i);
  // i>=4 -> row 256+rg*4+(i-4) (kk = 2+(rg>>5), same o). cols: bb=bbase+cgq, m=j.
  const int rgl = rg & 31;
  const int kkA = rg >> 5;
  int msA[8], msB[8];
#pragma unroll
  for (int r = 0; r < 8; r++) {
    msA[r] = idxL[cgq][kkA][r];
    msB[r] = idxL[cgq][2 + kkA][r];
  }
  float yp[4][8];
#pragma unroll
  for (int i4 = 0; i4 < 4; i4++) {
#pragma unroll
    for (int r = 0; r < 8; r++) {
      float v = 0.f;
#pragma unroll
      for (int j = 0; j < 8; j++) {
        v += (j == msA[r]) ? acc[i4][j] : 0.f;
        v += (j == msB[r]) ? acc[i4 + 4][j] : 0.f;
      }
      yp[i4][r] = v;
    }
  }
#pragma unroll
  for (int i4 = 0; i4 < 4; i4++)
#pragma unroll
    for (int r = 0; r < 8; r++) yp[i4][r] += __shfl_xor(yp[i4][r], 32);
  if (rg < 32) {
    float* dst = y32 + ((size_t)(bbase + cgq) * 32 + blockIdx.x) * 1024 + rgl * 32;
#pragma unroll
    for (int i4 = 0; i4 < 4; i4++) {
      float4 v0 = {yp[i4][0], yp[i4][1], yp[i4][2], yp[i4][3]};
      float4 v1 = {yp[i4][4], yp[i4][5], yp[i4][6], yp[i4][7]};
      *(float4*)(dst + i4 * 8) = v0;
      *(float4*)(dst + i4 * 8 + 4) = v1;
    }
  }
}

// ============================================================
// Kernel E1: y[f] = leaky(sum_kt y32[b][kt][f] + b_sp[f>>3]); fc1 -> h1.
// grid (B, 8), 256 thr; wave-per-output, coalesced 4KB weight rows.
// ============================================================
__global__ __launch_bounds__(256) void kE1(
    const float* __restrict__ y32, const float* __restrict__ b_sp,
    const float* __restrict__ fc1_w, const float* __restrict__ fc1_b,
    float* __restrict__ h1) {
  __shared__ float yl[1024];
  int b = blockIdx.x, og = blockIdx.y, tid = threadIdx.x;
  {
    int f0 = tid * 4;
    const float* base = y32 + (size_t)b * 32768 + f0;
    float a0 = 0, a1 = 0, a2 = 0, a3 = 0;
    float b0 = 0, b1v = 0, b2v = 0, b3v = 0;
#pragma unroll
    for (int kt = 0; kt < 32; kt += 2) {
      float4 u = *(const float4*)(base + (size_t)kt * 1024);
      float4 w = *(const float4*)(base + (size_t)(kt + 1) * 1024);
      a0 += u.x; a1 += u.y; a2 += u.z; a3 += u.w;
      b0 += w.x; b1v += w.y; b2v += w.z; b3v += w.w;
    }
    float bias = b_sp[tid >> 1];  // f>>3 = (tid*4+j)>>3 = tid>>1 for j<4? no:
    // careful: f = tid*4 + j, f>>3 = (tid*4+j)>>3 -> depends on j only via tid parity
    float v[4] = {a0 + b0, a1 + b1v, a2 + b2v, a3 + b3v};
    float o[4];
#pragma unroll
    for (int j = 0; j < 4; j++) {
      int f = f0 + j;
      float s = v[j] + b_sp[f >> 3];
      o[j] = LEAKY(s);
    }
    (void)bias;
    float4 vv = {o[0], o[1], o[2], o[3]};
    *(float4*)(yl + f0) = vv;
  }
  __syncthreads();
  int wid = tid >> 6, lane = tid & 63;
  const float4* ylv = (const float4*)yl;
#pragma unroll
  for (int pass = 0; pass < 16; pass++) {
    int o = og * 64 + pass * 4 + wid;
    const float4* wr = (const float4*)(fc1_w + (size_t)o * 1024);
    float sa = 0, sb = 0, sc = 0, sd = 0;
#pragma unroll
    for (int r = 0; r < 4; r++) {
      float4 w = wr[r * 64 + lane];
      float4 u = ylv[r * 64 + lane];
      sa = fmaf(w.x, u.x, sa); sb = fmaf(w.y, u.y, sb);
      sc = fmaf(w.z, u.z, sc); sd = fmaf(w.w, u.w, sd);
    }
    float s = (sa + sb) + (sc + sd);
#pragma unroll
    for (int d = 1; d < 64; d <<= 1) s += __shfl_xor(s, d);
    if (lane == 0) {
      float t = s + fc1_b[o];
      h1[(size_t)b * 512 + o] = LEAKY(t);
    }
  }
}

// ============================================================
// Kernel E2: fc2 -> heads. grid (B), 256 thr.
// ============================================================
__global__ __launch_bounds__(256) void kE2(
    const float* __restrict__ h1, const float* __restrict__ fc2_w,
    const float* __restrict__ fc2_b,
    const float* __restrict__ fcr_w, const float* __restrict__ fcr_b,
    const float* __restrict__ fct_w, const float* __restrict__ fct_b,
    float* __restrict__ out) {
  __shared__ float h1l[512];
  __shared__ float h2[256];
  int b = blockIdx.x, tid = threadIdx.x;
  if (tid < 128) {
    float4 v = *(const float4*)(h1 + (size_t)b * 512 + tid * 4);
    *(float4*)(h1l + tid * 4) = v;
  }
  __syncthreads();
  {
    int o = tid;
    const float4* wr = (const float4*)(fc2_w + (size_t)o * 512);
    const float4* uv = (const float4*)h1l;
    float sa = 0, sb = 0, sc = 0, sd = 0;
#pragma unroll 4
    for (int q = 0; q < 128; q++) {
      float4 w = wr[q];
      float4 u = uv[q];
      sa = fmaf(w.x, u.x, sa); sb = fmaf(w.y, u.y, sb);
      sc = fmaf(w.z, u.z, sc); sd = fmaf(w.w, u.w, sd);
    }
    float s = (sa + sb) + (sc + sd) + fc2_b[o];
    h2[o] = LEAKY(s);
  }
  __syncthreads();
  if (tid < 7) {
    bool isrot = tid < 4;
    int o = isrot ? tid : tid - 4;
    const float4* wr = (const float4*)((isrot ? fcr_w : fct_w) + (size_t)o * 256);
    const float4* uv = (const float4*)h2;
    float sa = 0, sb = 0, sc = 0, sd = 0;
#pragma unroll 4
    for (int q = 0; q < 64; q++) {
      float4 w = wr[q];
      float4 u = uv[q];
      sa = fmaf(w.x, u.x, sa); sb = fmaf(w.y, u.y, sb);
      sc = fmaf(w.z, u.z, sc); sd = fmaf(w.w, u.w, sd);
    }
    float s = (sa + sb) + (sc + sd) + (isrot ? fcr_b[o] : fct_b[o]);
    out[isrot ? (b * 4 + o) : (128 + b * 3 + o)] = s;
  }
}

extern "C" void kernel_launch(void* const* d_in, const int* in_sizes, int n_in,
                              void* d_out, int out_size, void* d_ws, size_t ws_size,
                              hipStream_t stream) {
  const float* coor    = (const float*)d_in[0];
  const float* region  = (const float*)d_in[1];
  const float* extents = (const float*)d_in[2];
  const float* w1 = (const float*)d_in[3];  const float* b1 = (const float*)d_in[4];
  const float* w2 = (const float*)d_in[5];  const float* b2 = (const float*)d_in[6];
  const float* w3 = (const float*)d_in[7];  const float* b3 = (const float*)d_in[8];
  const float* w_sp = (const float*)d_in[9];  const float* b_sp = (const float*)d_in[10];
  const float* fc1_w = (const float*)d_in[11]; const float* fc1_b = (const float*)d_in[12];
  const float* fc2_w = (const float*)d_in[13]; const float* fc2_b = (const float*)d_in[14];
  const float* fcr_w = (const float*)d_in[15]; const float* fcr_b = (const float*)d_in[16];
  const float* fct_w = (const float*)d_in[17]; const float* fct_b = (const float*)d_in[18];

  char* ws = (char*)d_ws;
  float* xs   = (float*)(ws + OFF_XS);
  int*   idx  = (int*)(ws + OFF_IDX);
  unsigned* pool = (unsigned*)(ws + OFF_POOL);
  unsigned short* wsp = (unsigned short*)(ws + OFF_WSP);
  float* y32  = (float*)(ws + OFF_Y32);
  float* h1   = (float*)(ws + OFF_IDX);  // aliases idx: written after kC consumed idx
  float* out  = (float*)d_out;

  hipMemsetAsync(pool, 0, (size_t)NBATCH * 1024 * 4, stream);  // enc(x) > 0 for all finite x
  kW<<<dim3(128), 256, 0, stream>>>(w2, w3, wsp);
  kA<<<dim3(NTILES, NBATCH), 256, 0, stream>>>(coor, region, extents,
                                               w1, b1, b2, b3, wsp, pool);
  kB<<<dim3(NBATCH), 256, 0, stream>>>(pool, xs, idx);
  kC<<<dim3(32, 8), 256, 0, stream>>>(xs, w_sp, idx, y32);
  kE1<<<dim3(NBATCH, 8), 256, 0, stream>>>(y32, b_sp, fc1_w, fc1_b, h1);
  kE2<<<dim3(NBATCH), 256, 0, stream>>>(h1, fc2_w, fc2_b, fcr_w, fcr_b,
                                        fct_w, fct_b, out);
}